// Round 20
// baseline (2521.341 us; speedup 1.0000x reference)
//
#include <hip/hip_runtime.h>
#include <hip/hip_bf16.h>
#include <math.h>

#define D_IN   2048
#define D_SAE  16384
#define NROWS  4096   // B*2
#define KTOP   64
#define HDIM   8192
#define CHUNK  1024
#define EPSN   1e-8f
#define BANDW_F16 4e-3f   // >=10 sigma of fp16 screen error
#define BANDW_F32 4e-4f   // fallback path
#define BANDCAP 512
#define NTILE   128       // n-tiles per row
#define SEG     16        // slots per (row, n-tile) segment
#define CAPT    (NTILE*SEG)   // 2048 total slots per row
#define TH_CAND 2.0f      // candidate floor (v64 >= 2.50 whp; certified in-kernel)

typedef unsigned short u16;
typedef unsigned char u8;
typedef _Float16 f16;
typedef __attribute__((ext_vector_type(8))) _Float16 f16x8;
typedef __attribute__((ext_vector_type(4))) _Float16 f16x4;
typedef __attribute__((ext_vector_type(8))) unsigned short u16x8;
typedef __attribute__((ext_vector_type(4))) float float4v;
typedef __attribute__((ext_vector_type(2))) float f32x2;

__device__ __forceinline__ unsigned f2u(float f) {
  unsigned b = __float_as_uint(f);
  return (b & 0x80000000u) ? ~b : (b | 0x80000000u);
}
__device__ __forceinline__ float u2f(unsigned u) {
  unsigned b = (u & 0x80000000u) ? (u & 0x7fffffffu) : ~u;
  return __uint_as_float(b);
}
__device__ __forceinline__ u16 f2bf_rne(float f) {
  unsigned b = __float_as_uint(f);
  unsigned r = (b + 0x7fffu + ((b >> 16) & 1u)) >> 16;
  return (u16)r;
}
__device__ __forceinline__ float bf2f(u16 u) {
  return __uint_as_float(((unsigned)u) << 16);
}
__device__ __forceinline__ void async_copy16(void* lds, const void* g) {
  __builtin_amdgcn_global_load_lds(
      (const __attribute__((address_space(1))) unsigned*)(g),
      (__attribute__((address_space(3))) unsigned*)(lds), 16, 0, 0);
}

// ---- fused preprocessing: splitT_w (bid<8192) + split_x (bid>=8192) --------
__global__ __launch_bounds__(256)
void pre_kernel(const float* __restrict__ x, const float* __restrict__ W,
                f16* __restrict__ Axh, f16* __restrict__ Th,
                float* __restrict__ WT)
{
  __shared__ float S[64][65];
  const int bid = blockIdx.x;
  if (bid < 8192) {
    const int tx = threadIdx.x & 63, ty = threadIdx.x >> 6;
    const int n0 = (bid & 255) * 64, k0 = (bid >> 8) * 64;
#pragma unroll
    for (int i = 0; i < 16; ++i) {
      int kl = ty + i * 4;
      S[kl][tx] = W[(size_t)(k0 + kl) * D_SAE + n0 + tx];
    }
    __syncthreads();
#pragma unroll
    for (int i = 0; i < 16; ++i) {
      int nl = ty + i * 4;
      float v = S[tx][nl];               // = W[k0+tx][n0+nl]
      Th[(size_t)(n0 + nl) * D_IN + k0 + tx] = (f16)v;
      WT[(size_t)(n0 + nl) * D_IN + k0 + tx] = v;
    }
  } else {
    int t = (bid - 8192) * 256 + threadIdx.x;   // 4 elems per thread
    const int n4 = (NROWS * D_IN) / 4;
    if (t < n4) {
      float4 v = ((const float4*)x)[t];
      f16x4 h;
      h.x = (f16)v.x; h.y = (f16)v.y; h.z = (f16)v.z; h.w = (f16)v.w;
      ((f16x4*)Axh)[t] = h;
    }
  }
}

// -- fp16 MFMA screen GEMM: 256x256, BK=32, 4-phase counted-vmcnt, 2 blk/CU --
// 512 thr (8 waves 2Mx4N); K=2048 as 64 tiles of BK=32; iteration = 2 tiles,
// 4 phases.  LDS: As/Bs[2 dbuf][2 half][128 x 32] fp16 = 64 KiB -> 2
// blocks/CU (cross-block overlap hides barrier/lgkm stalls).  Per phase:
// {ds_read subtile || stage half-tiles (1 issue/thread each) -> s_barrier ->
// setprio(1) 16xMFMA setprio(0) -> [vmcnt] -> s_barrier}.  vmcnt(2) at
// phases 2+4 (steady-state queue oldest-first = [B_prev x2, A_prev x2,
// B_next x2]; wait-to-2 retires exactly what the next phase reads);
// vmcnt(0) guards the tail.  Swizzle slot = fsl ^ ((rl>>1)&3): 16 lanes
// cover all 8 (row-parity, slot) bank positions twice -> 2-way = free.
__global__ __launch_bounds__(512, 4)
void gemm_f16_kernel(const f16* __restrict__ Axh,  // [4096][2048]
                     const f16* __restrict__ BT,   // [16384][2048]
                     const float* __restrict__ bias,
                     unsigned* __restrict__ ckey_g, // [NROWS][NTILE][SEG]
                     u16* __restrict__ cidx_g,      // [NROWS][NTILE][SEG]
                     unsigned* __restrict__ ccnt)   // [NROWS][NTILE]
{
  __shared__ u16 As[2][2][128 * 32];   // [dbuf][half][rl*32 + col(swizzled)]
  __shared__ u16 Bs[2][2][128 * 32];
  const int tid  = threadIdx.x;
  const int wave = tid >> 6, lane = tid & 63;
  const int bid  = blockIdx.x;
  const int xcd  = bid & 7, loc = bid >> 3;
  const int n0   = (xcd * 8 + (loc >> 4)) * 256;
  const int m0   = (loc & 15) * 256;
  const int wr   = wave >> 2;          // 0..1 (M half -> A LDS half)
  const int wc   = wave & 3;           // 0..3 (N quarter; B LDS half = wc>>1)
  const int fr   = lane & 15;
  const int fsl  = lane >> 4;          // 0..3

  float4v acc[8][4];                   // [mhq*4+mi][nhq*2+nj]
#pragma unroll
  for (int i = 0; i < 8; ++i)
#pragma unroll
    for (int j = 0; j < 4; ++j) acc[i][j] = (float4v){0.f, 0.f, 0.f, 0.f};

  // element offsets into a [128][32] slab (slot-swizzled, k-invariant)
  int aofs[2][4], bofs[2][2];
#pragma unroll
  for (int mhq = 0; mhq < 2; ++mhq)
#pragma unroll
    for (int mi = 0; mi < 4; ++mi) {
      int rl = mhq * 64 + mi * 16 + fr;
      aofs[mhq][mi] = rl * 32 + ((fsl ^ ((rl >> 1) & 3)) * 8);
    }
#pragma unroll
  for (int nhq = 0; nhq < 2; ++nhq)
#pragma unroll
    for (int nj = 0; nj < 2; ++nj) {
      int cl = (wc & 1) * 64 + nhq * 32 + nj * 16 + fr;
      bofs[nhq][nj] = cl * 32 + ((fsl ^ ((cl >> 1) & 3)) * 8);
    }

  f16x8 a[4], b[2][2];                 // a[mi], b[nhq][nj]

  auto rdA = [&](int d, int mhq) {
#pragma unroll
    for (int mi = 0; mi < 4; ++mi)
      a[mi] = *(const f16x8*)&As[d][wr][aofs[mhq][mi]];
  };
  auto rdB = [&](int d, int nhq) {
#pragma unroll
    for (int nj = 0; nj < 2; ++nj)
      b[nhq][nj] = *(const f16x8*)&Bs[d][wc >> 1][bofs[nhq][nj]];
  };
  auto domfma = [&](int mhq, int nhq) {
#pragma unroll
    for (int mi = 0; mi < 4; ++mi)
#pragma unroll
      for (int nj = 0; nj < 2; ++nj)
        acc[mhq*4+mi][nhq*2+nj] = __builtin_amdgcn_mfma_f32_16x16x32_f16(
            a[mi], b[nhq][nj], acc[mhq*4+mi][nhq*2+nj], 0, 0, 0);
  };
  // stage one half-tile (128 rows x 32 cols fp16 = 8 KiB) = 1 issue/thread
  auto stage = [&](u16* base, const f16* grow, int tt) {
    int rl = tid >> 2, sl = tid & 3;
    int gc = tt * 32 + ((sl ^ ((rl >> 1) & 3)) * 8);
    async_copy16((char*)base + (size_t)tid * 16,
                 grow + (size_t)rl * D_IN + gc);
  };
  const f16* Ah0 = Axh + (size_t)m0 * D_IN;
  const f16* Ah1 = Axh + (size_t)(m0 + 128) * D_IN;
  const f16* Bh0 = BT + (size_t)n0 * D_IN;
  const f16* Bh1 = BT + (size_t)(n0 + 128) * D_IN;

  // prologue: tile0 (A+B) + B of tile1; A of tile1 arrives in P1 of j=0
  stage(&As[0][0][0], Ah0, 0); stage(&As[0][1][0], Ah1, 0);
  stage(&Bs[0][0][0], Bh0, 0); stage(&Bs[0][1][0], Bh1, 0);
  stage(&Bs[1][0][0], Bh0, 1); stage(&Bs[1][1][0], Bh1, 1);
  asm volatile("s_waitcnt vmcnt(0)" ::: "memory");
  __builtin_amdgcn_s_barrier();

#pragma unroll 1
  for (int j = 0; j < 32; ++j) {
    const int t1 = 2 * j + 1, t2 = 2 * j + 2, t3 = 2 * j + 3;
    const bool g = (j < 31);
    // P1: rd a(mh0)+b(both) of dbuf0; issue A(t1) both halves
    rdA(0, 0); rdB(0, 0); rdB(0, 1);
    stage(&As[1][0][0], Ah0, t1);
    stage(&As[1][1][0], Ah1, t1);
    __builtin_amdgcn_s_barrier();
    __builtin_amdgcn_s_setprio(1);
    domfma(0, 0);
    domfma(0, 1);
    __builtin_amdgcn_s_setprio(0);
    __builtin_amdgcn_s_barrier();
    // P2: rd a(mh1) of dbuf0; issue B(t2) both halves; vmcnt
    rdA(0, 1);
    if (g) { stage(&Bs[0][0][0], Bh0, t2); stage(&Bs[0][1][0], Bh1, t2); }
    __builtin_amdgcn_s_barrier();
    __builtin_amdgcn_s_setprio(1);
    domfma(1, 0);
    domfma(1, 1);
    __builtin_amdgcn_s_setprio(0);
    if (g) { asm volatile("s_waitcnt vmcnt(2)" ::: "memory"); }
    else   { asm volatile("s_waitcnt vmcnt(0)" ::: "memory"); }
    __builtin_amdgcn_s_barrier();
    // P3: rd a(mh0)+b(both) of dbuf1; issue A(t2)
    rdA(1, 0); rdB(1, 0); rdB(1, 1);
    if (g) { stage(&As[0][0][0], Ah0, t2); stage(&As[0][1][0], Ah1, t2); }
    __builtin_amdgcn_s_barrier();
    __builtin_amdgcn_s_setprio(1);
    domfma(0, 0);
    domfma(0, 1);
    __builtin_amdgcn_s_setprio(0);
    __builtin_amdgcn_s_barrier();
    // P4: rd a(mh1) of dbuf1; issue B(t3); vmcnt
    rdA(1, 1);
    if (g) { stage(&Bs[1][0][0], Bh0, t3); stage(&Bs[1][1][0], Bh1, t3); }
    __builtin_amdgcn_s_barrier();
    __builtin_amdgcn_s_setprio(1);
    domfma(1, 0);
    domfma(1, 1);
    __builtin_amdgcn_s_setprio(0);
    if (g) { asm volatile("s_waitcnt vmcnt(2)" ::: "memory"); }
    else   { asm volatile("s_waitcnt vmcnt(0)" ::: "memory"); }
    __builtin_amdgcn_s_barrier();
  }
  __syncthreads();

  // ---- epilogue: candidate emission (lcnt[2 tiles][256 rows] in dead As) ---
  unsigned* lcnt = (unsigned*)&As[0][0][0];
  lcnt[tid] = 0u;
  __syncthreads();
  const int tl = wc >> 1;                 // n-tile local (0/1)
  const int tileG = (n0 >> 7) + tl;
  const int orow = (lane >> 4) * 4;
#pragma unroll
  for (int mi = 0; mi < 8; ++mi) {
#pragma unroll
    for (int nj = 0; nj < 4; ++nj) {
      int col = n0 + wc * 64 + (nj >> 1) * 32 + (nj & 1) * 16 + fr;
      float bv = bias[col];
#pragma unroll
      for (int rr = 0; rr < 4; ++rr) {
        float val = acc[mi][nj][rr] + bv;
        if (val >= TH_CAND) {
          int lrow = wr * 128 + (mi >> 2) * 64 + (mi & 3) * 16 + orow + rr; // 0..255
          unsigned j = atomicAdd(&lcnt[tl * 256 + lrow], 1u);
          if (j < SEG) {
            size_t sb = ((size_t)(m0 + lrow) * NTILE + tileG) * SEG;
            ckey_g[sb + j] = f2u(val);
            cidx_g[sb + j] = (u16)col;
          }
        }
      }
    }
  }
  __syncthreads();
  ccnt[(size_t)(m0 + (tid & 255)) * NTILE + (n0 >> 7) + (tid >> 8)] = lcnt[tid];
}

// ---- select: batched gather + bucket-select + certified band resolve -------
__global__ __launch_bounds__(256)
void select_compact_kernel(const unsigned* __restrict__ ckey_g,
                           const u16* __restrict__ cidx_g,
                           const unsigned* __restrict__ ccnt,
                           const float* __restrict__ x,
                           const float* __restrict__ WT,
                           const float* __restrict__ benc,
                           float bandw,
                           int*   __restrict__ topk_idx,
                           float* __restrict__ topk_val,
                           float* __restrict__ nh_norm,
                           unsigned* __restrict__ flags)
{
  __shared__ unsigned ckey[CAPT];
  __shared__ u16      cidx[CAPT];
  __shared__ unsigned tof[128];
  __shared__ unsigned tc[128];
  __shared__ unsigned hist[256];
  __shared__ unsigned sscan[257];
  __shared__ unsigned wsum[4];
  __shared__ float    bv_l[64];
  __shared__ int      band_idx[BANDCAP];
  __shared__ float    band_val[BANDCAP];
  __shared__ double   band_ex[BANDCAP];
  __shared__ unsigned char picked[BANDCAP];
  __shared__ int      out_idx[64];
  __shared__ float    out_val[64];
  __shared__ float    sh_v64;
  __shared__ unsigned sh_mcnt, sh_bstar, sh_kth, sh_ocnt, sh_bcnt, sh_bad;

  const int tid = threadIdx.x;
  const int wv = tid >> 6, ln = tid & 63;
  const int r = blockIdx.x;

  if (tid == 0) { sh_ocnt = 0u; sh_bcnt = 0u; sh_bad = 0u; sh_mcnt = 0u; sh_bstar = 0xffffffffu; }
  hist[tid] = 0u;
  if (tid < 128) {
    unsigned c = ccnt[(size_t)r * NTILE + tid];
    tc[tid] = c;
    if (c > SEG) sh_bad = 1u;   // benign race
  }
  __syncthreads();
  // inclusive prefix of tc -> tof (shuffle scan, 2 waves + combine)
  if (tid < 128) {
    unsigned v = tc[tid];
#pragma unroll
    for (int d = 1; d < 64; d <<= 1) {
      unsigned t = __shfl_up(v, d);
      if (ln >= d) v += t;
    }
    tof[tid] = v;
  }
  __syncthreads();
  if (tid >= 64 && tid < 128) tof[tid] += tof[63];
  __syncthreads();
  const unsigned cc_u = tof[127];
  const int cc = (int)(cc_u < CAPT ? cc_u : CAPT);

  // batched coalesced gather: issue all loads before any LDS store
  {
    unsigned ck[8]; u16 ci[8]; unsigned pv[8];
#pragma unroll
    for (int b = 0; b < 8; ++b) {
      int idx = tid + 256 * b;
      int tile = idx >> 4, slot = idx & 15;
      unsigned c = tc[tile]; if (c > SEG) c = SEG;
      bool valid = (unsigned)slot < c;
      pv[b] = valid ? (tof[tile] - tc[tile] + slot) : 0xffffffffu;
      ck[b] = valid ? ckey_g[(size_t)r * CAPT + idx] : 0u;
      ci[b] = valid ? cidx_g[(size_t)r * CAPT + idx] : (u16)0;
    }
#pragma unroll
    for (int b = 0; b < 8; ++b) {
      if (pv[b] < (unsigned)CAPT) { ckey[pv[b]] = ck[b]; cidx[pv[b]] = ci[b]; }
    }
  }
  __syncthreads();

  bool bad = (sh_bad != 0u) || (cc_u < 64u) || (cc_u > (unsigned)CAPT);

  // bucket histogram (0.01-wide value buckets over [2.0, 4.56))
  if (!bad) {
    for (int s = tid; s < cc; s += 256) {
      float v = u2f(ckey[s]);
      int b = (int)((v - TH_CAND) * 100.0f);
      b = b < 0 ? 0 : (b > 255 ? 255 : b);
      atomicAdd(&hist[b], 1u);
    }
  }
  __syncthreads();
  // suffix scan via shuffle: sscan[b] = # entries in buckets >= b
  {
    int rt = 255 - tid;
    unsigned v = hist[rt];
#pragma unroll
    for (int d = 1; d < 64; d <<= 1) {
      unsigned t = __shfl_up(v, d);
      if (ln >= d) v += t;
    }
    if (ln == 63) wsum[wv] = v;
    __syncthreads();
    unsigned add = 0;
    for (int w = 0; w < wv; ++w) add += wsum[w];
    sscan[rt] = v + add;
    if (tid == 0) sscan[256] = 0u;
    __syncthreads();
    if (sscan[tid] >= 64u && sscan[tid + 1] < 64u) {
      sh_bstar = (unsigned)tid;
      sh_kth = 64u - sscan[tid + 1];
    }
  }
  __syncthreads();

  if (bad || sh_bstar == 0xffffffffu) { if (tid == 0) flags[r] = 1u; return; }
  const int bstar = (int)sh_bstar;
  const unsigned kth = sh_kth;

  // collect bucket-b* values (expected ~2-4)
  for (int s = tid; s < cc; s += 256) {
    float v = u2f(ckey[s]);
    int b = (int)((v - TH_CAND) * 100.0f);
    b = b < 0 ? 0 : (b > 255 ? 255 : b);
    if (b == bstar) {
      unsigned p = atomicAdd(&sh_mcnt, 1u);
      if (p < 64u) bv_l[p] = v;
    }
  }
  __syncthreads();
  if (sh_mcnt > 64u) { if (tid == 0) flags[r] = 1u; return; }
  const int m = (int)sh_mcnt;
  // exact v64 = kth largest within bucket (strict order w/ index tiebreak)
  if (wv == 0 && ln < m) {
    float mine = bv_l[ln];
    int rank = 0;
    for (int j = 0; j < m; ++j) {
      float o = bv_l[j];
      if (o > mine || (o == mine && j < ln)) ++rank;
    }
    if (rank == (int)kth - 1) sh_v64 = mine;
  }
  __syncthreads();
  const float v64 = sh_v64;

  // classify
  const float hi = v64 + 2.f * bandw, lo = v64 - 2.f * bandw;
  for (int s = tid; s < cc; s += 256) {
    float v = u2f(ckey[s]);
    int i = (int)cidx[s];
    if (v > hi) {
      unsigned p = atomicAdd(&sh_ocnt, 1u);
      out_idx[p] = i; out_val[p] = v;
    } else if (v >= lo) {
      unsigned p = atomicAdd(&sh_bcnt, 1u);
      if (p < BANDCAP) { band_idx[p] = i; band_val[p] = v; }
    }
  }
  __syncthreads();
  if (sh_bcnt > BANDCAP) { if (tid == 0) flags[r] = 1u; return; }
  const unsigned nci = sh_ocnt;                       // <= 63
  const unsigned bcnt = sh_bcnt;
  const unsigned remaining = 64u - nci;               // >= 1; bcnt >= remaining

  if (bcnt == remaining) {
    for (unsigned s = tid; s < bcnt; s += 256) {
      out_idx[nci + s] = band_idx[s];
      out_val[nci + s] = band_val[s];
    }
    __syncthreads();
  } else {
    // exact fp64 recompute of band entries (wave-parallel, 8-deep batched)
    const float* xr = x + (size_t)r * 2048;
    for (unsigned bi = wv; bi < bcnt; bi += 4) {
      int c = band_idx[bi];
      const float* wr = WT + (size_t)c * 2048;
      double s = 0.0;
      for (int j0 = 0; j0 < 2048; j0 += 512) {
        float xa[8], wa[8];
#pragma unroll
        for (int u = 0; u < 8; ++u) {
          int j = j0 + ln + 64 * u;
          xa[u] = xr[j];
          wa[u] = wr[j];
        }
#pragma unroll
        for (int u = 0; u < 8; ++u)
          s += (double)xa[u] * (double)wa[u];
      }
#pragma unroll
      for (int off2 = 32; off2 > 0; off2 >>= 1)
        s += __shfl_down(s, off2);
      if (ln == 0) band_ex[bi] = s + (double)benc[c];
    }
    __syncthreads();
    if (tid == 0) {
      for (unsigned i2 = 0; i2 < bcnt; ++i2) picked[i2] = 0;
      for (unsigned s = 0; s < remaining; ++s) {
        int best = -1;
        for (unsigned b2 = 0; b2 < bcnt; ++b2) {
          if (picked[b2]) continue;
          if (best < 0 || band_ex[b2] > band_ex[best] ||
              (band_ex[b2] == band_ex[best] && band_idx[b2] < band_idx[best]))
            best = (int)b2;
        }
        picked[best] = 1;
        out_idx[nci + s] = band_idx[best];
        out_val[nci + s] = (float)band_ex[best];
      }
    }
    __syncthreads();
  }

  if (tid < 64) {
    float v = out_val[tid];
    v = v > 0.f ? v : 0.f;
    out_val[tid] = v;
    topk_idx[(size_t)r * 64 + tid] = out_idx[tid];
    topk_val[(size_t)r * 64 + tid] = v;
  }
  __syncthreads();
  if (tid == 0) {
    float n2 = 0.f;
    for (int s = 0; s < 64; ++s)
      if (out_idx[s] < HDIM) n2 += out_val[s] * out_val[s];
    nh_norm[r] = sqrtf(n2);
    flags[r] = 0u;
  }
}

// ---- repair: full recompute for flagged rows (P ~ 0) -----------------------
__global__ __launch_bounds__(256)
void repair_kernel(const unsigned* __restrict__ flags,
                   const float* __restrict__ x,
                   const float* __restrict__ WT,
                   const float* __restrict__ benc,
                   int* __restrict__ topk_idx,
                   float* __restrict__ topk_val,
                   float* __restrict__ nh_norm)
{
  const int r = blockIdx.x;
  if (flags[r] == 0u) return;
  __shared__ float prerow[16384];   // 64 KB
  __shared__ float xs[2048];
  __shared__ float rv[256];
  __shared__ int   ri[256];
  __shared__ int   oi[64];
  __shared__ float ov[64];
  const int tid = threadIdx.x;
  for (int i = tid; i < 2048; i += 256) xs[i] = x[(size_t)r * 2048 + i];
  __syncthreads();
  for (int c = tid; c < 16384; c += 256) {
    const float* wr = WT + (size_t)c * 2048;
    float s = 0.f;
    for (int j = 0; j < 2048; ++j) s = fmaf(xs[j], wr[j], s);
    prerow[c] = s + benc[c];
  }
  __syncthreads();
  for (int k2 = 0; k2 < 64; ++k2) {
    float bv = -INFINITY; int bi = 16384;
    for (int c = tid; c < 16384; c += 256) {
      float v = prerow[c];
      if (v > bv || (v == bv && c < bi)) { bv = v; bi = c; }
    }
    rv[tid] = bv; ri[tid] = bi;
    __syncthreads();
    for (int s2 = 128; s2 > 0; s2 >>= 1) {
      if (tid < s2) {
        if (rv[tid+s2] > rv[tid] || (rv[tid+s2] == rv[tid] && ri[tid+s2] < ri[tid])) {
          rv[tid] = rv[tid+s2]; ri[tid] = ri[tid+s2];
        }
      }
      __syncthreads();
    }
    if (tid == 0) { oi[k2] = ri[0]; ov[k2] = rv[0]; prerow[ri[0]] = -INFINITY; }
    __syncthreads();
  }
  if (tid < 64) {
    float v = ov[tid]; v = v > 0.f ? v : 0.f;
    topk_idx[(size_t)r * 64 + tid] = oi[tid];
    topk_val[(size_t)r * 64 + tid] = v;
  }
  __syncthreads();
  if (tid == 0) {
    float n2 = 0.f;
    for (int s = 0; s < 64; ++s)
      if (oi[s] < HDIM) { float v = ov[s] > 0.f ? ov[s] : 0.f; n2 += v * v; }
    nh_norm[r] = sqrtf(n2);
  }
}

// -- fused: wdec fp32->fp8 (bid<16384) + ZpTb scatter for even rows (else) ---
__global__ __launch_bounds__(256)
void wdec_scatter_kernel(const float* __restrict__ W,
                         u8* __restrict__ W8, float* __restrict__ scl,
                         const int* __restrict__ topk_idx,
                         const float* __restrict__ topk_val,
                         const float* __restrict__ nh_norm,
                         u16* __restrict__ ZpTb)
{
  const int bid = blockIdx.x;
  const int tid = threadIdx.x;
  if (bid < 16384) {
    __shared__ float red[256];
    const int c = bid;
    const int e0 = tid * 8;
    const float* wr = W + (size_t)c * 2048;
    float4 a = *(const float4*)(wr + e0);
    float4 b = *(const float4*)(wr + e0 + 4);
    float w[8] = {a.x,a.y,a.z,a.w,b.x,b.y,b.z,b.w};
    float mx = 0.f;
#pragma unroll
    for (int i = 0; i < 8; ++i) mx = fmaxf(mx, fabsf(w[i]));
    red[tid] = mx; __syncthreads();
    for (int s = 128; s > 0; s >>= 1) { if (tid < s) red[tid] = fmaxf(red[tid], red[tid+s]); __syncthreads(); }
    const float mxa = red[0];
    const float senc = mxa > 0.f ? 448.f / mxa : 0.f;
    float q[8];
#pragma unroll
    for (int i = 0; i < 8; ++i) q[i] = fminf(fmaxf(w[i] * senc, -448.f), 448.f);
    int p0 = __builtin_amdgcn_cvt_pk_fp8_f32(q[0], q[1], 0, false);
    p0 = __builtin_amdgcn_cvt_pk_fp8_f32(q[2], q[3], p0, true);
    int p1 = __builtin_amdgcn_cvt_pk_fp8_f32(q[4], q[5], 0, false);
    p1 = __builtin_amdgcn_cvt_pk_fp8_f32(q[6], q[7], p1, true);
    uint2 o; o.x = (unsigned)p0; o.y = (unsigned)p1;
    *(uint2*)(W8 + (size_t)c * 2048 + e0) = o;
    if (tid == 0) scl[c] = mxa > 0.f ? mxa / 448.f : 0.f;
  } else {
    // even-row ZpTb scatter: t indexes 2048 even rows x 64 slots
    int t = (bid - 16384) * 256 + tid;
    if (t < 2048 * 64) {
      int b = t >> 6;                 // 0..2047
      int r = 2 * b;                  // even row
      int c = topk_idx[(size_t)r * 64 + (t & 63)];
      float v = topk_val[(size_t)r * 64 + (t & 63)];
      if (c < HDIM) {
        float nrm = nh_norm[r]; nrm = nrm > EPSN ? nrm : EPSN;
        ZpTb[(size_t)c * 2048 + b] = f2bf_rne(v / nrm);
      }
    }
  }
}

// -- fused token kernel: decode + SE (all rows); odd rows additionally write
//    dense z_cur row, x_hat, sim row, lse_row, diag.
__global__ __launch_bounds__(256)
void token_kernel(const int* __restrict__ topk_idx,
                  const float* __restrict__ topk_val,
                  const u8* __restrict__ W8,      // fp8 [16384][2048]
                  const float* __restrict__ scl,  // [16384]
                  const float* __restrict__ bdec,
                  const float* __restrict__ x,
                  const float* __restrict__ nh_norm,
                  const u16* __restrict__ ZpTb,   // bf16 [8192][2048]
                  float* __restrict__ se_full,
                  float* __restrict__ se_high,
                  float* __restrict__ xhat_out,
                  float* __restrict__ zcur_out,
                  float* __restrict__ simb,
                  float* __restrict__ lse_row,
                  float* __restrict__ diag)
{
  __shared__ int sidx[64];
  __shared__ float sval[64];
  __shared__ float rawv[64];
  __shared__ float red[256];
  __shared__ int cidx2[64];
  __shared__ float cval2[64];
  __shared__ u8 zmap[16384];
  __shared__ int scnt;
  const int tid = threadIdx.x;
  const int r = blockIdx.x;
  const int e0 = tid * 8;
  const bool odd = (r & 1);
  if (tid == 0) scnt = 0;
  if (odd) {
    unsigned* zm = (unsigned*)zmap;
#pragma unroll
    for (int j = 0; j < 16; ++j) zm[tid + 256 * j] = 0xFFFFFFFFu;
  }
  if (tid < 64) {
    int c = topk_idx[(size_t)r*64+tid];
    float v = topk_val[(size_t)r*64+tid];
    sidx[tid] = c;
    rawv[tid] = v;
    sval[tid] = v * scl[c];
  }
  __syncthreads();
  if (odd && tid < 64) zmap[sidx[tid]] = (u8)tid;   // distinct indices
  float accf[8], acch[8];
  {
    float4 b0 = *(const float4*)(bdec + e0);
    float4 b1 = *(const float4*)(bdec + e0 + 4);
    accf[0]=b0.x; accf[1]=b0.y; accf[2]=b0.z; accf[3]=b0.w;
    accf[4]=b1.x; accf[5]=b1.y; accf[6]=b1.z; accf[7]=b1.w;
#pragma unroll
    for (int i = 0; i < 8; ++i) acch[i] = accf[i];
  }
  for (int s0 = 0; s0 < 64; s0 += 8) {
    uint2 w[8]; float vf[8], vh[8];
#pragma unroll
    for (int j = 0; j < 8; ++j) {
      int c = sidx[s0 + j];
      float v = sval[s0 + j];
      vf[j] = v;
      vh[j] = (c < HDIM) ? v : 0.f;
      w[j] = *(const uint2*)(W8 + (size_t)c * 2048 + e0);
    }
#pragma unroll
    for (int j = 0; j < 8; ++j) {
      f32x2 f0 = __builtin_amdgcn_cvt_pk_f32_fp8((int)w[j].x, false);
      f32x2 f1 = __builtin_amdgcn_cvt_pk_f32_fp8((int)w[j].x, true);
      f32x2 f2 = __builtin_amdgcn_cvt_pk_f32_fp8((int)w[j].y, false);
      f32x2 f3 = __builtin_amdgcn_cvt_pk_f32_fp8((int)w[j].y, true);
      float wvv[8] = {f0[0],f0[1],f1[0],f1[1],f2[0],f2[1],f3[0],f3[1]};
#pragma unroll
      for (int i = 0; i < 8; ++i) {
        accf[i] = fmaf(vf[j], wvv[i], accf[i]);
        acch[i] = fmaf(vh[j], wvv[i], acch[i]);
      }
    }
  }
  const float* xr = x + (size_t)r * 2048;
  float4 x0 = *(const float4*)(xr + e0);
  float4 x1 = *(const float4*)(xr + e0 + 4);
  float xv[8] = {x0.x,x0.y,x0.z,x0.w,x1.x,x1.y,x1.z,x1.w};
  float sf = 0.f, shs = 0.f;
#pragma unroll
  for (int i = 0; i < 8; ++i) {
    float df = accf[i] - xv[i]; sf += df*df;
    float dh = acch[i] - xv[i]; shs += dh*dh;
  }
  red[tid] = sf; __syncthreads();
  for (int s2=128; s2>0; s2>>=1){ if (tid<s2) red[tid]+=red[tid+s2]; __syncthreads(); }
  if (tid==0) se_full[r] = red[0];
  __syncthreads();
  red[tid] = shs; __syncthreads();
  for (int s2=128; s2>0; s2>>=1){ if (tid<s2) red[tid]+=red[tid+s2]; __syncthreads(); }
  if (tid==0) se_high[r] = red[0];
  if (!odd) return;

  // ---- odd row: dense z_cur row write + x_hat, then sim row + lse_row ----
  {
    float* orow = xhat_out + (size_t)(r >> 1) * 2048;
    float4 o0 = {accf[0],accf[1],accf[2],accf[3]};
    float4 o1 = {accf[4],accf[5],accf[6],accf[7]};
    *(float4*)(orow + e0) = o0;
    *(float4*)(orow + e0 + 4) = o1;
  }
  {
    float* zrow = zcur_out + (size_t)(r >> 1) * 16384;
#pragma unroll
    for (int it = 0; it < 16; ++it) {
      int c0 = it * 1024 + tid * 4;
      float4 o;
      u8 s0m = zmap[c0 + 0]; o.x = (s0m < 64) ? rawv[s0m] : 0.f;
      u8 s1m = zmap[c0 + 1]; o.y = (s1m < 64) ? rawv[s1m] : 0.f;
      u8 s2m = zmap[c0 + 2]; o.z = (s2m < 64) ? rawv[s2m] : 0.f;
      u8 s3m = zmap[c0 + 3]; o.w = (s3m < 64) ? rawv[s3m] : 0.f;
      *(float4*)(zrow + c0) = o;
    }
  }
  const int i = r >> 1;
  __syncthreads();
  if (tid < 64) {
    int c = sidx[tid];
    float v = rawv[tid];
    if (c < HDIM) {
      float nrm = nh_norm[r]; nrm = nrm > EPSN ? nrm : EPSN;
      int p = atomicAdd(&scnt, 1);
      cidx2[p] = c; cval2[p] = v / nrm;
    }
  }
  __syncthreads();
  float acc[8];
#pragma unroll
  for (int ii = 0; ii < 8; ++ii) acc[ii] = 0.f;
  const int m = scnt;
  int s = 0;
  for (; s + 8 <= m; s += 8) {
    u16x8 z[8]; float vv[8];
#pragma unroll
    for (int j = 0; j < 8; ++j) {
      vv[j] = cval2[s + j];
      z[j] = *(const u16x8*)(ZpTb + (size_t)cidx2[s + j] * 2048 + e0);
    }
#pragma unroll
    for (int j = 0; j < 8; ++j)
#pragma unroll
      for (int ii = 0; ii < 8; ++ii)
        acc[ii] = fmaf(vv[j], bf2f(z[j][ii]), acc[ii]);
  }
  for (; s < m; ++s) {
    int c = cidx2[s]; float v = cval2[s];
    u16x8 z8 = *(const u16x8*)(ZpTb + (size_t)c * 2048 + e0);
#pragma unroll
    for (int ii = 0; ii < 8; ++ii)
      acc[ii] = fmaf(v, bf2f(z8[ii]), acc[ii]);
  }
  {
    float* srow = simb + (size_t)i * 2048;
    float4 o0 = {acc[0],acc[1],acc[2],acc[3]};
    float4 o1 = {acc[4],acc[5],acc[6],acc[7]};
    *(float4*)(srow + e0) = o0;
    *(float4*)(srow + e0 + 4) = o1;
  }
  // fused lse_row + diag (acc holds sim[i][e0..e0+7])
  float mx = -INFINITY;
#pragma unroll
  for (int ii = 0; ii < 8; ++ii) mx = fmaxf(mx, acc[ii]);
  if ((i >> 3) == tid) diag[i] = acc[i & 7];
  red[tid] = mx; __syncthreads();
  for (int s2=128; s2>0; s2>>=1){ if (tid<s2) red[tid]=fmaxf(red[tid],red[tid+s2]); __syncthreads(); }
  mx = red[0]; __syncthreads();
  float se = 0.f;
#pragma unroll
  for (int ii = 0; ii < 8; ++ii) se += expf(acc[ii] - mx);
  red[tid] = se; __syncthreads();
  for (int s2=128; s2>0; s2>>=1){ if (tid<s2) red[tid]+=red[tid+s2]; __syncthreads(); }
  if (tid == 0) lse_row[i] = mx + logf(red[0]);
}

// ---------------- fp32 tiled GEMM (fallback) -------------------------------
__global__ __launch_bounds__(256)
void gemm_pre_kernel(const float* __restrict__ A,
                     const float* __restrict__ B,
                     const float* __restrict__ bias,
                     float* __restrict__ C)
{
  __shared__ float As[16][129];
  __shared__ float Bs[16][129];
  const int tid = threadIdx.x;
  const int tx = tid & 15, ty = tid >> 4;
  const int m0 = blockIdx.y * 128;
  const int n0 = blockIdx.x * 128;
  float acc[8][8];
#pragma unroll
  for (int i = 0; i < 8; ++i)
#pragma unroll
    for (int j = 0; j < 8; ++j) acc[i][j] = 0.f;
  const int lk = tid & 15, lm = tid >> 4;
  for (int k0 = 0; k0 < 2048; k0 += 16) {
#pragma unroll
    for (int i = 0; i < 8; ++i) {
      int m = lm + 16 * i;
      As[lk][m] = A[(size_t)(m0 + m) * 2048 + k0 + lk];
    }
#pragma unroll
    for (int i = 0; i < 8; ++i) {
      int idx = tid + 256 * i;
      int kk = idx >> 7, nn = idx & 127;
      Bs[kk][nn] = B[(size_t)(k0 + kk) * 16384 + n0 + nn];
    }
    __syncthreads();
#pragma unroll
    for (int kk = 0; kk < 16; ++kk) {
      float a[8], b[8];
#pragma unroll
      for (int i = 0; i < 8; ++i) a[i] = As[kk][ty + 16 * i];
#pragma unroll
      for (int j = 0; j < 8; ++j) b[j] = Bs[kk][tx + 16 * j];
#pragma unroll
      for (int i = 0; i < 8; ++i)
#pragma unroll
        for (int j = 0; j < 8; ++j) acc[i][j] = fmaf(a[i], b[j], acc[i][j]);
    }
    __syncthreads();
  }
#pragma unroll
  for (int i = 0; i < 8; ++i) {
    int m = m0 + ty + 16 * i;
#pragma unroll
    for (int j = 0; j < 8; ++j) {
      int n = n0 + tx + 16 * j;
      C[(size_t)m * 16384 + n] = acc[i][j] + bias[n];
    }
  }
}

// ---------------- fallback select (fp32 screen, strided resolve) ------------
__global__ __launch_bounds__(256)
void select_fb_kernel(const float* __restrict__ pre,
                      const float* __restrict__ x,
                      const float* __restrict__ Wenc,
                      const float* __restrict__ benc,
                      int row_base, float bandw,
                      int*   __restrict__ topk_idx,
                      float* __restrict__ topk_val,
                      float* __restrict__ nh_norm)
{
  __shared__ unsigned hist[256];
  __shared__ int      band_idx[BANDCAP];
  __shared__ double   band_ex[BANDCAP];
  __shared__ double   red_d[256];
  __shared__ int      out_idx[64];
  __shared__ float    out_val[64];
  __shared__ unsigned char picked[BANDCAP];
  __shared__ unsigned sh_prefix, sh_need, sh_ocnt, sh_bcnt;

  const int tid = threadIdx.x;
  const int lrow = blockIdx.x;
  const int row = row_base + lrow;
  const float* prow = pre + (size_t)lrow * 16384;

  if (tid == 0) { sh_prefix = 0u; sh_need = 64u; }
  __syncthreads();
  for (int level = 24; level >= 0; level -= 8) {
    hist[tid] = 0u;
    __syncthreads();
    unsigned prefix = sh_prefix;
    for (int i = tid; i < 16384; i += 256) {
      unsigned u = f2u(prow[i]);
      bool match = (level == 24) || ((u >> ((level + 8) & 31)) == prefix);
      if (match) atomicAdd(&hist[(u >> level) & 255u], 1u);
    }
    __syncthreads();
    if (tid == 0) {
      unsigned need = sh_need, acc = 0; int q = 0;
      for (int b2 = 255; b2 >= 0; --b2) {
        if (acc + hist[b2] >= need) { q = b2; break; }
        acc += hist[b2];
      }
      sh_prefix = (prefix << 8) | (unsigned)q;
      sh_need = need - acc;
    }
    __syncthreads();
  }
  const float v64 = u2f(sh_prefix);

  if (tid == 0) { sh_ocnt = 0u; sh_bcnt = 0u; }
  __syncthreads();
  const float hi = v64 + 2.f * bandw, lo = v64 - 2.f * bandw;
  for (int i = tid; i < 16384; i += 256) {
    float v = prow[i];
    if (v > hi) {
      unsigned p = atomicAdd(&sh_ocnt, 1u);
      out_idx[p] = i; out_val[p] = v;
    } else if (v >= lo) {
      unsigned p = atomicAdd(&sh_bcnt, 1u);
      if (p < BANDCAP) { band_idx[p] = i; }
    }
  }
  __syncthreads();
  const unsigned nci = sh_ocnt;
  const unsigned bcnt = sh_bcnt < BANDCAP ? sh_bcnt : BANDCAP;
  const unsigned remaining = 64u - nci;

  if (bcnt == remaining) {
    for (unsigned s = tid; s < bcnt; s += 256) {
      int c = band_idx[s];
      out_idx[nci + s] = c;
      out_val[nci + s] = prow[c];
    }
    __syncthreads();
  } else {
    const float* xr = x + (size_t)row * 2048;
    for (unsigned bi = 0; bi < bcnt; ++bi) {
      int c = band_idx[bi];
      double part = 0.0;
#pragma unroll
      for (int j2 = 0; j2 < 8; ++j2) {
        int kk = tid + 256 * j2;
        part += (double)xr[kk] * (double)Wenc[(size_t)kk * 16384 + c];
      }
      red_d[tid] = part;
      __syncthreads();
      for (int sft = 128; sft > 0; sft >>= 1) {
        if (tid < sft) red_d[tid] += red_d[tid + sft];
        __syncthreads();
      }
      if (tid == 0) band_ex[bi] = red_d[0] + (double)benc[c];
      __syncthreads();
    }
    if (tid == 0) {
      for (unsigned i2 = 0; i2 < bcnt; ++i2) picked[i2] = 0;
      for (unsigned s = 0; s < remaining; ++s) {
        int best = -1;
        for (unsigned b2 = 0; b2 < bcnt; ++b2) {
          if (picked[b2]) continue;
          if (best < 0 || band_ex[b2] > band_ex[best] ||
              (band_ex[b2] == band_ex[best] && band_idx[b2] < band_idx[best]))
            best = (int)b2;
        }
        picked[best] = 1;
        out_idx[nci + s] = band_idx[best];
        out_val[nci + s] = (float)band_ex[best];
      }
    }
    __syncthreads();
  }

  if (tid < 64) {
    float v = out_val[tid];
    v = v > 0.f ? v : 0.f;
    out_val[tid] = v;
    topk_idx[(size_t)row * 64 + tid] = out_idx[tid];
    topk_val[(size_t)row * 64 + tid] = v;
  }
  __syncthreads();
  if (tid == 0) {
    float n2 = 0.f;
    for (int s = 0; s < 64; ++s)
      if (out_idx[s] < HDIM) n2 += out_val[s] * out_val[s];
    nh_norm[row] = sqrtf(n2);
  }
}

__global__ __launch_bounds__(256)
void scatter_f32_kernel(const int* __restrict__ topk_idx,
                        const float* __restrict__ topk_val,
                        const float* __restrict__ nh_norm,
                        float* __restrict__ zcur_out,
                        float* __restrict__ ZpT)
{
  int t = blockIdx.x * blockDim.x + threadIdx.x;
  if (t >= NROWS * 64) return;
  int r = t >> 6;
  int c = topk_idx[t];
  float v = topk_val[t];
  int b = r >> 1;
  if (r & 1) {
    zcur_out[(size_t)b * 16384 + c] = v;
  } else if (c < HDIM) {
    float nrm = nh_norm[r]; nrm = nrm > EPSN ? nrm : EPSN;
    ZpT[(size_t)c * 2048 + b] = v / nrm;
  }
}

__global__ __launch_bounds__(256)
void decode_f32_kernel(const int* __restrict__ topk_idx,
                       const float* __restrict__ topk_val,
                       const float* __restrict__ Wdec,
                       const float* __restrict__ bdec,
                       const float* __restrict__ x,
                       float* __restrict__ se_full,
                       float* __restrict__ se_high,
                       float* __restrict__ xhat_out)
{
  __shared__ int sidx[64];
  __shared__ float sval[64];
  __shared__ float red[256];
  const int tid = threadIdx.x;
  const int r = blockIdx.x;
  if (tid < 64) { sidx[tid] = topk_idx[(size_t)r*64+tid]; sval[tid] = topk_val[(size_t)r*64+tid]; }
  __syncthreads();
  float accf[8], acch[8];
#pragma unroll
  for (int i = 0; i < 8; ++i) { float b = bdec[tid + 256*i]; accf[i] = b; acch[i] = b; }
  for (int s = 0; s < 64; ++s) {
    int c = sidx[s]; float v = sval[s];
    const float* wr = Wdec + (size_t)c * 2048;
    bool high = (c < HDIM);
#pragma unroll
    for (int i = 0; i < 8; ++i) {
      float w = wr[tid + 256*i];
      accf[i] = fmaf(v, w, accf[i]);
      if (high) acch[i] = fmaf(v, w, acch[i]);
    }
  }
  const float* xr = x + (size_t)r * 2048;
  float sf = 0.f, shs = 0.f;
#pragma unroll
  for (int i = 0; i < 8; ++i) {
    float xv = xr[tid + 256*i];
    float df = accf[i] - xv; sf += df*df;
    float dh = acch[i] - xv; shs += dh*dh;
  }
  red[tid] = sf; __syncthreads();
  for (int s2=128; s2>0; s2>>=1){ if (tid<s2) red[tid]+=red[tid+s2]; __syncthreads(); }
  if (tid==0) se_full[r] = red[0];
  __syncthreads();
  red[tid] = shs; __syncthreads();
  for (int s2=128; s2>0; s2>>=1){ if (tid<s2) red[tid]+=red[tid+s2]; __syncthreads(); }
  if (tid==0) se_high[r] = red[0];
  if (r & 1) {
    float* orow = xhat_out + (size_t)(r >> 1) * 2048;
#pragma unroll
    for (int i = 0; i < 8; ++i) orow[tid + 256*i] = accf[i];
  }
}

__global__ __launch_bounds__(256)
void sim_f32_kernel(const int* __restrict__ topk_idx,
                    const float* __restrict__ topk_val,
                    const float* __restrict__ nh_norm,
                    const float* __restrict__ ZpT,
                    float* __restrict__ sim)
{
  __shared__ int cidx2[64];
  __shared__ float cval2[64];
  __shared__ int scnt;
  const int tid = threadIdx.x;
  const int i = blockIdx.x;
  const int r = 2 * i + 1;
  if (tid == 0) scnt = 0;
  __syncthreads();
  if (tid < 64) {
    int c = topk_idx[(size_t)r*64+tid];
    float v = topk_val[(size_t)r*64+tid];
    if (c < HDIM) {
      float nrm = nh_norm[r]; nrm = nrm > EPSN ? nrm : EPSN;
      int p = atomicAdd(&scnt, 1);
      cidx2[p] = c; cval2[p] = v / nrm;
    }
  }
  __syncthreads();
  float acc[8];
#pragma unroll
  for (int ii = 0; ii < 8; ++ii) acc[ii] = 0.f;
  int m = scnt;
  for (int s = 0; s < m; ++s) {
    int c = cidx2[s]; float v = cval2[s];
    const float* zr = ZpT + (size_t)c * 2048;
#pragma unroll
    for (int ii = 0; ii < 8; ++ii)
      acc[ii] = fmaf(v, zr[tid + 256*ii], acc[ii]);
  }
  float* srow = sim + (size_t)i * 2048;
#pragma unroll
  for (int ii = 0; ii < 8; ++ii) srow[tid + 256*ii] = acc[ii];
}

// lse_row (fallback path only; main path fuses it into token_kernel)
__global__ __launch_bounds__(256)
void lse_row_kernel(const float* __restrict__ sim,
                    float* __restrict__ lse_row, float* __restrict__ diag)
{
  __shared__ float red[256];
  const int tid = threadIdx.x; const int i = blockIdx.x;
  const int e0 = tid * 8;
  const float* srow = sim + (size_t)i * 2048;
  float4 v0 = *(const float4*)(srow + e0);
  float4 v1 = *(const float4*)(srow + e0 + 4);
  float vals[8] = {v0.x,v0.y,v0.z,v0.w,v1.x,v1.y,v1.z,v1.w};
  float mx = -INFINITY;
#pragma unroll
  for (int ii=0; ii<8; ++ii) mx = fmaxf(mx, vals[ii]);
  if ((i >> 3) == tid) diag[i] = vals[i & 7];
  red[tid]=mx; __syncthreads();
  for (int s=128;s>0;s>>=1){ if (tid<s) red[tid]=fmaxf(red[tid],red[tid+s]); __syncthreads(); }
  mx = red[0]; __syncthreads();
  float se=0.f;
#pragma unroll
  for (int ii=0;ii<8;++ii) se += expf(vals[ii]-mx);
  red[tid]=se; __syncthreads();
  for (int s=128;s>0;s>>=1){ if (tid<s) red[tid]+=red[tid+s]; __syncthreads(); }
  if (tid==0) lse_row[i] = mx + logf(red[0]);
}

// coalesced online-softmax over columns: 256 blocks x 8 cols, 32 row-thr/col
__global__ __launch_bounds__(256)
void lse_col_kernel(const float* __restrict__ sim, float* __restrict__ lse_col)
{
  __shared__ float ml[32][9], sl[32][9];
  const int tid = threadIdx.x;
  const int c = tid & 7, rr = tid >> 3;
  const int col = blockIdx.x * 8 + c;
  float m = -INFINITY, s = 0.f;
  for (int r = rr; r < 2048; r += 32) {
    float v = sim[(size_t)r * 2048 + col];
    float mn = fmaxf(m, v);
    s = s * expf(m - mn) + expf(v - mn);
    m = mn;
  }
  ml[rr][c] = m; sl[rr][c] = s;
  __syncthreads();
  if (rr == 0) {
    float M = ml[0][c];
#pragma unroll
    for (int i = 1; i < 32; ++i) M = fmaxf(M, ml[i][c]);
    float S = 0.f;
#pragma unroll
    for (int i = 0; i < 32; ++i) S += sl[i][c] * expf(ml[i][c] - M);
    lse_col[col] = M + logf(S);
  }
}

// ---------------- final scalar ----------------------------------------------
__global__ __launch_bounds__(256)
void final_kernel(const float* __restrict__ se_full, const float* __restrict__ se_high,
                  const float* __restrict__ lse_row, const float* __restrict__ lse_col,
                  const float* __restrict__ diag, float* __restrict__ out0)
{
  __shared__ float red[256];
  const int tid = threadIdx.x;
  float s1 = 0.f;
  for (int i = tid; i < 4096; i += 256) s1 += se_full[i] + se_high[i];
  red[tid]=s1; __syncthreads();
  for (int s=128;s>0;s>>=1){ if (tid<s) red[tid]+=red[tid+s]; __syncthreads(); }
  float matr = red[0]; __syncthreads();
  float s2 = 0.f;
  for (int i = tid; i < 2048; i += 256) s2 += (lse_row[i]-diag[i]) + (lse_col[i]-diag[i]);
  red[tid]=s2; __syncthreads();
  for (int s=128;s>0;s>>=1){ if (tid<s) red[tid]+=red[tid+s]; __syncthreads(); }
  if (tid == 0) {
    float l_matr  = matr / (2048.f * 2048.f);
    float l_contr = 0.5f * (red[0] / 2048.f);
    out0[0] = l_matr + l_contr;
  }
}

extern "C" void kernel_launch(void* const* d_in, const int* in_sizes, int n_in,
                              void* d_out, int out_size, void* d_ws, size_t ws_size,
                              hipStream_t stream)
{
  const float* x    = (const float*)d_in[0];
  const float* Wenc = (const float*)d_in[1];
  const float* Wdec = (const float*)d_in[2];
  const float* benc = (const float*)d_in[3];
  const float* bdec = (const float*)d_in[4];
  float* out = (float*)d_out;
  float* xhat_out = out + 1;
  float* zcur_out = out + 1 + (size_t)2048 * 2048;
  (void)in_sizes; (void)n_in; (void)out_size;

  char* ws = (char*)d_ws;
  size_t off = 0;
  auto alloc = [&](size_t bytes) {
    char* p = ws + off; off += (bytes + 255) & ~(size_t)255; return p;
  };
  int*      tki     = (int*)     alloc((size_t)NROWS * 64 * 4);
  float*    tkv     = (float*)   alloc((size_t)NROWS * 64 * 4);
  float*    nh_norm = (float*)   alloc((size_t)NROWS * 4);
  float*    se_f    = (float*)   alloc((size_t)NROWS * 4);
  float*    se_h    = (float*)   alloc((size_t)NROWS * 4);
  float*    lse_r   = (float*)   alloc((size_t)2048 * 4);
  float*    lse_c   = (float*)   alloc((size_t)2048 * 4);
  float*    diag    = (float*)   alloc((size_t)2048 * 4);
  f16*      Axh     = (f16*)     alloc((size_t)NROWS * D_IN * 2);      // 16 MiB
  unsigned* ckey_g  = (unsigned*)alloc((size_t)NROWS * CAPT * 4);      // 32 MiB
  u16*      cidx_g  = (u16*)     alloc((size_t)NROWS * CAPT * 2);      // 16 MiB
  unsigned* ccnt    = (unsigned*)alloc((size_t)NROWS * NTILE * 4);     //  2 MiB
  unsigned* flags   = (unsigned*)alloc((size_t)NROWS * 4);
  char*     R1      = alloc((size_t)D_SAE * D_IN * 2);                 // 64 MiB: Th -> {W8, scl}
  char*     R2      = alloc((size_t)D_SAE * D_IN * 4);                 // 128 MiB: WT -> ZpTb+sim
  size_t need = off;

  f16*   Th    = (f16*)R1;
  u8*    W8    = (u8*)R1;                                       // 32 MiB
  float* scl   = (float*)(R1 + (size_t)D_SAE * D_IN);           // 64 KiB
  float* WT    = (float*)R2;
  u16*   ZpTb  = (u16*)R2;                                      // 32 MiB
  float* simb  = (float*)(R2 + (size_t)8192 * 2048 * 2);        // 16 MiB

  if (ws_size >= need) {
    // ---- fp16 MFMA screen -> segmented candidate lists -> certified select --
    pre_kernel<<<16384, 256, 0, stream>>>(x, Wenc, Axh, Th, WT);
    gemm_f16_kernel<<<1024, 512, 0, stream>>>(Axh, Th, benc, ckey_g, cidx_g, ccnt);
    select_compact_kernel<<<NROWS, 256, 0, stream>>>(ckey_g, cidx_g, ccnt, x, WT, benc,
        BANDW_F16, tki, tkv, nh_norm, flags);
    repair_kernel<<<NROWS, 256, 0, stream>>>(flags, x, WT, benc, tki, tkv, nh_norm);
    // Th dead after gemm; WT dead after repair (stream-ordered)
    hipMemsetAsync(ZpTb, 0, (size_t)8192 * 2048 * 2, stream);
    wdec_scatter_kernel<<<16384 + 512, 256, 0, stream>>>(Wdec, W8, scl,
        tki, tkv, nh_norm, ZpTb);
    token_kernel<<<NROWS, 256, 0, stream>>>(tki, tkv, W8, scl, bdec, x, nh_norm, ZpTb,
        se_f, se_h, xhat_out, zcur_out, simb, lse_r, diag);
    lse_col_kernel<<<256, 256, 0, stream>>>(simb, lse_c);
    final_kernel<<<1, 256, 0, stream>>>(se_f, se_h, lse_r, lse_c, diag, out);
  } else {
    // ---- fp32 fallback (smaller footprint) ----
    off = 0;
    float* pre2  = (float*)alloc((size_t)CHUNK * 16384 * 4);
    int*   tki2  = (int*)  alloc((size_t)NROWS * 64 * 4);
    float* tkv2  = (float*)alloc((size_t)NROWS * 64 * 4);
    float* nh2   = (float*)alloc((size_t)NROWS * 4);
    float* sef2  = (float*)alloc((size_t)NROWS * 4);
    float* seh2  = (float*)alloc((size_t)NROWS * 4);
    float* lr2   = (float*)alloc((size_t)2048 * 4);
    float* lc2   = (float*)alloc((size_t)2048 * 4);
    float* dg2   = (float*)alloc((size_t)2048 * 4);
    float* ZpT2  = (float*)alloc((size_t)8192 * 2048 * 4);
    float* sim2  = (float*)alloc((size_t)2048 * 2048 * 4);
    hipMemsetAsync(zcur_out, 0, (size_t)2048 * 16384 * 4, stream);
    for (int ch = 0; ch < 4; ++ch) {
      dim3 g(128, 8);
      gemm_pre_kernel<<<g, 256, 0, stream>>>(x + (size_t)ch * CHUNK * 2048, Wenc, benc, pre2);
      select_fb_kernel<<<CHUNK, 256, 0, stream>>>(pre2, x, Wenc, benc,
          ch * CHUNK, BANDW_F32, tki2, tkv2, nh2);
    }
    hipMemsetAsync(ZpT2, 0, (size_t)8192 * 2048 * 4, stream);
    scatter_f32_kernel<<<(NROWS * 64) / 256, 256, 0, stream>>>(tki2, tkv2, nh2, zcur_out, ZpT2);
    decode_f32_kernel<<<NROWS, 256, 0, stream>>>(tki2, tkv2, Wdec, bdec, x, sef2, seh2, xhat_out);
    sim_f32_kernel<<<2048, 256, 0, stream>>>(tki2, tkv2, nh2, ZpT2, sim2);
    lse_row_kernel<<<2048, 256, 0, stream>>>(sim2, lr2, dg2);
    lse_col_kernel<<<256, 256, 0, stream>>>(sim2, lc2);
    final_kernel<<<1, 256, 0, stream>>>(sef2, seh2, lr2, lc2, dg2, out);
  }
}

// Round 21
// 636.105 us; speedup vs baseline: 3.9637x; 3.9637x over previous
//
#include <hip/hip_runtime.h>
#include <hip/hip_bf16.h>
#include <math.h>

#define D_IN   2048
#define D_SAE  16384
#define NROWS  4096   // B*2
#define KTOP   64
#define HDIM   8192
#define CHUNK  1024
#define EPSN   1e-8f
#define BANDW_F16 4e-3f   // >=10 sigma of fp16 screen error
#define BANDW_F32 4e-4f   // fallback path
#define BANDCAP 512
#define NTILE   128       // n-tiles per row
#define SEG     16        // slots per (row, n-tile) segment
#define CAPT    (NTILE*SEG)   // 2048 total slots per row
#define TH_CAND 2.0f      // candidate floor (v64 >= 2.50 whp; certified in-kernel)

typedef unsigned short u16;
typedef unsigned char u8;
typedef _Float16 f16;
typedef __attribute__((ext_vector_type(8))) _Float16 f16x8;
typedef __attribute__((ext_vector_type(4))) _Float16 f16x4;
typedef __attribute__((ext_vector_type(8))) unsigned short u16x8;
typedef __attribute__((ext_vector_type(4))) float float4v;
typedef __attribute__((ext_vector_type(2))) float f32x2;

__device__ __forceinline__ unsigned f2u(float f) {
  unsigned b = __float_as_uint(f);
  return (b & 0x80000000u) ? ~b : (b | 0x80000000u);
}
__device__ __forceinline__ float u2f(unsigned u) {
  unsigned b = (u & 0x80000000u) ? (u & 0x7fffffffu) : ~u;
  return __uint_as_float(b);
}
__device__ __forceinline__ u16 f2bf_rne(float f) {
  unsigned b = __float_as_uint(f);
  unsigned r = (b + 0x7fffu + ((b >> 16) & 1u)) >> 16;
  return (u16)r;
}
__device__ __forceinline__ float bf2f(u16 u) {
  return __uint_as_float(((unsigned)u) << 16);
}
__device__ __forceinline__ void async_copy16(void* lds, const void* g) {
  __builtin_amdgcn_global_load_lds(
      (const __attribute__((address_space(1))) unsigned*)(g),
      (__attribute__((address_space(3))) unsigned*)(lds), 16, 0, 0);
}

// ---- fused preprocessing: splitT_w (bid<8192) + split_x (bid>=8192) --------
__global__ __launch_bounds__(256)
void pre_kernel(const float* __restrict__ x, const float* __restrict__ W,
                f16* __restrict__ Axh, f16* __restrict__ Th,
                float* __restrict__ WT)
{
  __shared__ float S[64][65];
  const int bid = blockIdx.x;
  if (bid < 8192) {
    const int tx = threadIdx.x & 63, ty = threadIdx.x >> 6;
    const int n0 = (bid & 255) * 64, k0 = (bid >> 8) * 64;
#pragma unroll
    for (int i = 0; i < 16; ++i) {
      int kl = ty + i * 4;
      S[kl][tx] = W[(size_t)(k0 + kl) * D_SAE + n0 + tx];
    }
    __syncthreads();
#pragma unroll
    for (int i = 0; i < 16; ++i) {
      int nl = ty + i * 4;
      float v = S[tx][nl];               // = W[k0+tx][n0+nl]
      Th[(size_t)(n0 + nl) * D_IN + k0 + tx] = (f16)v;
      WT[(size_t)(n0 + nl) * D_IN + k0 + tx] = v;
    }
  } else {
    int t = (bid - 8192) * 256 + threadIdx.x;   // 4 elems per thread
    const int n4 = (NROWS * D_IN) / 4;
    if (t < n4) {
      float4 v = ((const float4*)x)[t];
      f16x4 h;
      h.x = (f16)v.x; h.y = (f16)v.y; h.z = (f16)v.z; h.w = (f16)v.w;
      ((f16x4*)Axh)[t] = h;
    }
  }
}

// -- fp16 MFMA screen GEMM: 256x256, 4-phase counted-vmcnt schedule ----------
// 512 thr (8 waves 2Mx4N); K=2048 as 32 tiles of BK=64; iteration = 2 tiles,
// 4 phases (merged from the 8-phase template: same data movement and issue
// rotation, half the barrier crossings).  LDS: As/Bs[2 dbuf][2 half]
// [128 x 64] fp16 = 128 KiB.  Per phase: {ds_read subtiles || stage 2
// half-tiles -> s_barrier -> setprio(1) 32xMFMA setprio(0) -> [vmcnt] ->
// s_barrier}; B-frags live in regs across M-halves.  vmcnt(4) at phases
// 2+4 only (rotation: P1=A(2j+1); P2=B(2j+2); P3=A(2j+2); P4=B(2j+3));
// vmcnt(0) guards the tail.  Buffer-transition safety: all dbuf-X ds_reads
// complete before the P2/P4-end barrier that precedes any dbuf-X restage.
__global__ __launch_bounds__(512, 1)
void gemm_f16_kernel(const f16* __restrict__ Axh,  // [4096][2048]
                     const f16* __restrict__ BT,   // [16384][2048]
                     const float* __restrict__ bias,
                     unsigned* __restrict__ ckey_g, // [NROWS][NTILE][SEG]
                     u16* __restrict__ cidx_g,      // [NROWS][NTILE][SEG]
                     unsigned* __restrict__ ccnt)   // [NROWS][NTILE]
{
  __shared__ u16 As[2][2][128 * 64];   // [dbuf][half][rl*64 + col(swizzled)]
  __shared__ u16 Bs[2][2][128 * 64];
  const int tid  = threadIdx.x;
  const int wave = tid >> 6, lane = tid & 63;
  const int bid  = blockIdx.x;
  const int xcd  = bid & 7, loc = bid >> 3;
  const int n0   = (xcd * 8 + (loc >> 4)) * 256;
  const int m0   = (loc & 15) * 256;
  const int wr   = wave >> 2;          // 0..1 (M half -> A LDS half)
  const int wc   = wave & 3;           // 0..3 (N quarter; B LDS half = wc>>1)
  const int fr   = lane & 15;
  const int fsl  = lane >> 4;          // 0..3

  float4v acc[8][4];                   // [mhq*4+mi][nhq*2+nj]
#pragma unroll
  for (int i = 0; i < 8; ++i)
#pragma unroll
    for (int j = 0; j < 4; ++j) acc[i][j] = (float4v){0.f, 0.f, 0.f, 0.f};

  // element offsets into a [128][64] slab (slot-swizzled, k-invariant)
  int aofs[2][4][2], bofs[2][2][2];
#pragma unroll
  for (int mhq = 0; mhq < 2; ++mhq)
#pragma unroll
    for (int mi = 0; mi < 4; ++mi)
#pragma unroll
      for (int kk = 0; kk < 2; ++kk) {
        int rl = mhq * 64 + mi * 16 + fr;
        aofs[mhq][mi][kk] = rl * 64 + (((kk * 4 + fsl) ^ (rl & 7)) * 8);
      }
#pragma unroll
  for (int nhq = 0; nhq < 2; ++nhq)
#pragma unroll
    for (int nj = 0; nj < 2; ++nj)
#pragma unroll
      for (int kk = 0; kk < 2; ++kk) {
        int cl = (wc & 1) * 64 + nhq * 32 + nj * 16 + fr;
        bofs[nhq][nj][kk] = cl * 64 + (((kk * 4 + fsl) ^ (cl & 7)) * 8);
      }

  f16x8 a[4][2], b[2][2][2];           // a[mi][kk], b[nhq][nj][kk]

  auto rdA = [&](int d, int mhq) {
#pragma unroll
    for (int mi = 0; mi < 4; ++mi)
#pragma unroll
      for (int kk = 0; kk < 2; ++kk)
        a[mi][kk] = *(const f16x8*)&As[d][wr][aofs[mhq][mi][kk]];
  };
  auto rdB = [&](int d, int nhq) {
#pragma unroll
    for (int nj = 0; nj < 2; ++nj)
#pragma unroll
      for (int kk = 0; kk < 2; ++kk)
        b[nhq][nj][kk] = *(const f16x8*)&Bs[d][wc >> 1][bofs[nhq][nj][kk]];
  };
  auto domfma = [&](int mhq, int nhq) {
#pragma unroll
    for (int mi = 0; mi < 4; ++mi)
#pragma unroll
      for (int nj = 0; nj < 2; ++nj)
#pragma unroll
        for (int kk = 0; kk < 2; ++kk)
          acc[mhq*4+mi][nhq*2+nj] = __builtin_amdgcn_mfma_f32_16x16x32_f16(
              a[mi][kk], b[nhq][nj][kk], acc[mhq*4+mi][nhq*2+nj], 0, 0, 0);
  };
  // stage one half-tile (128 rows x 64 cols fp16) = 2 x 512-thread issues
  auto stage = [&](u16* base, const f16* grow, int tt) {
#pragma unroll
    for (int ig = 0; ig < 2; ++ig) {
      int idx = ig * 512 + tid;          // 0..1023
      int rl = idx >> 3, sl = idx & 7;
      int gc = tt * 64 + ((sl ^ (rl & 7)) * 8);
      async_copy16((char*)base + (size_t)idx * 16,
                   grow + (size_t)rl * D_IN + gc);
    }
  };
  const f16* Ah0 = Axh + (size_t)m0 * D_IN;
  const f16* Ah1 = Axh + (size_t)(m0 + 128) * D_IN;
  const f16* Bh0 = BT + (size_t)n0 * D_IN;
  const f16* Bh1 = BT + (size_t)(n0 + 128) * D_IN;

  // prologue: tile0 (A+B) + B of tile1; A of tile1 arrives in P1 of j=0
  stage(&As[0][0][0], Ah0, 0); stage(&As[0][1][0], Ah1, 0);
  stage(&Bs[0][0][0], Bh0, 0); stage(&Bs[0][1][0], Bh1, 0);
  stage(&Bs[1][0][0], Bh0, 1); stage(&Bs[1][1][0], Bh1, 1);
  asm volatile("s_waitcnt vmcnt(0)" ::: "memory");
  __builtin_amdgcn_s_barrier();

#pragma unroll 1
  for (int j = 0; j < 16; ++j) {
    const int t1 = 2 * j + 1, t2 = 2 * j + 2, t3 = 2 * j + 3;
    const bool g = (j < 15);
    // P1: rd a(mh0)+b(both) of dbuf0; issue A(t1) both halves
    rdA(0, 0); rdB(0, 0); rdB(0, 1);
    stage(&As[1][0][0], Ah0, t1);
    stage(&As[1][1][0], Ah1, t1);
    __builtin_amdgcn_s_barrier();
    __builtin_amdgcn_s_setprio(1);
    domfma(0, 0);
    domfma(0, 1);
    __builtin_amdgcn_s_setprio(0);
    __builtin_amdgcn_s_barrier();
    // P2: rd a(mh1) of dbuf0; issue B(t2) both halves; vmcnt
    rdA(0, 1);
    if (g) { stage(&Bs[0][0][0], Bh0, t2); stage(&Bs[0][1][0], Bh1, t2); }
    __builtin_amdgcn_s_barrier();
    __builtin_amdgcn_s_setprio(1);
    domfma(1, 0);
    domfma(1, 1);
    __builtin_amdgcn_s_setprio(0);
    if (g) { asm volatile("s_waitcnt vmcnt(4)" ::: "memory"); }
    else   { asm volatile("s_waitcnt vmcnt(0)" ::: "memory"); }
    __builtin_amdgcn_s_barrier();
    // P3: rd a(mh0)+b(both) of dbuf1; issue A(t2)
    rdA(1, 0); rdB(1, 0); rdB(1, 1);
    if (g) { stage(&As[0][0][0], Ah0, t2); stage(&As[0][1][0], Ah1, t2); }
    __builtin_amdgcn_s_barrier();
    __builtin_amdgcn_s_setprio(1);
    domfma(0, 0);
    domfma(0, 1);
    __builtin_amdgcn_s_setprio(0);
    __builtin_amdgcn_s_barrier();
    // P4: rd a(mh1) of dbuf1; issue B(t3); vmcnt
    rdA(1, 1);
    if (g) { stage(&Bs[1][0][0], Bh0, t3); stage(&Bs[1][1][0], Bh1, t3); }
    __builtin_amdgcn_s_barrier();
    __builtin_amdgcn_s_setprio(1);
    domfma(1, 0);
    domfma(1, 1);
    __builtin_amdgcn_s_setprio(0);
    if (g) { asm volatile("s_waitcnt vmcnt(4)" ::: "memory"); }
    else   { asm volatile("s_waitcnt vmcnt(0)" ::: "memory"); }
    __builtin_amdgcn_s_barrier();
  }
  __syncthreads();

  // ---- epilogue: candidate emission (lcnt[2 tiles][256 rows] in dead As) ---
  unsigned* lcnt = (unsigned*)&As[0][0][0];
  lcnt[tid] = 0u;
  __syncthreads();
  const int tl = wc >> 1;                 // n-tile local (0/1)
  const int tileG = (n0 >> 7) + tl;
  const int orow = (lane >> 4) * 4;
#pragma unroll
  for (int mi = 0; mi < 8; ++mi) {
#pragma unroll
    for (int nj = 0; nj < 4; ++nj) {
      int col = n0 + wc * 64 + (nj >> 1) * 32 + (nj & 1) * 16 + fr;
      float bv = bias[col];
#pragma unroll
      for (int rr = 0; rr < 4; ++rr) {
        float val = acc[mi][nj][rr] + bv;
        if (val >= TH_CAND) {
          int lrow = wr * 128 + (mi >> 2) * 64 + (mi & 3) * 16 + orow + rr; // 0..255
          unsigned j = atomicAdd(&lcnt[tl * 256 + lrow], 1u);
          if (j < SEG) {
            size_t sb = ((size_t)(m0 + lrow) * NTILE + tileG) * SEG;
            ckey_g[sb + j] = f2u(val);
            cidx_g[sb + j] = (u16)col;
          }
        }
      }
    }
  }
  __syncthreads();
  ccnt[(size_t)(m0 + (tid & 255)) * NTILE + (n0 >> 7) + (tid >> 8)] = lcnt[tid];
}

// ---- select: batched gather + bucket-select + certified band resolve -------
__global__ __launch_bounds__(256)
void select_compact_kernel(const unsigned* __restrict__ ckey_g,
                           const u16* __restrict__ cidx_g,
                           const unsigned* __restrict__ ccnt,
                           const float* __restrict__ x,
                           const float* __restrict__ WT,
                           const float* __restrict__ benc,
                           float bandw,
                           int*   __restrict__ topk_idx,
                           float* __restrict__ topk_val,
                           float* __restrict__ nh_norm,
                           unsigned* __restrict__ flags)
{
  __shared__ unsigned ckey[CAPT];
  __shared__ u16      cidx[CAPT];
  __shared__ unsigned tof[128];
  __shared__ unsigned tc[128];
  __shared__ unsigned hist[256];
  __shared__ unsigned sscan[257];
  __shared__ unsigned wsum[4];
  __shared__ float    bv_l[64];
  __shared__ int      band_idx[BANDCAP];
  __shared__ float    band_val[BANDCAP];
  __shared__ double   band_ex[BANDCAP];
  __shared__ unsigned char picked[BANDCAP];
  __shared__ int      out_idx[64];
  __shared__ float    out_val[64];
  __shared__ float    sh_v64;
  __shared__ unsigned sh_mcnt, sh_bstar, sh_kth, sh_ocnt, sh_bcnt, sh_bad;

  const int tid = threadIdx.x;
  const int wv = tid >> 6, ln = tid & 63;
  const int r = blockIdx.x;

  if (tid == 0) { sh_ocnt = 0u; sh_bcnt = 0u; sh_bad = 0u; sh_mcnt = 0u; sh_bstar = 0xffffffffu; }
  hist[tid] = 0u;
  if (tid < 128) {
    unsigned c = ccnt[(size_t)r * NTILE + tid];
    tc[tid] = c;
    if (c > SEG) sh_bad = 1u;   // benign race
  }
  __syncthreads();
  // inclusive prefix of tc -> tof (shuffle scan, 2 waves + combine)
  if (tid < 128) {
    unsigned v = tc[tid];
#pragma unroll
    for (int d = 1; d < 64; d <<= 1) {
      unsigned t = __shfl_up(v, d);
      if (ln >= d) v += t;
    }
    tof[tid] = v;
  }
  __syncthreads();
  if (tid >= 64 && tid < 128) tof[tid] += tof[63];
  __syncthreads();
  const unsigned cc_u = tof[127];
  const int cc = (int)(cc_u < CAPT ? cc_u : CAPT);

  // batched coalesced gather: issue all loads before any LDS store
  {
    unsigned ck[8]; u16 ci[8]; unsigned pv[8];
#pragma unroll
    for (int b = 0; b < 8; ++b) {
      int idx = tid + 256 * b;
      int tile = idx >> 4, slot = idx & 15;
      unsigned c = tc[tile]; if (c > SEG) c = SEG;
      bool valid = (unsigned)slot < c;
      pv[b] = valid ? (tof[tile] - tc[tile] + slot) : 0xffffffffu;
      ck[b] = valid ? ckey_g[(size_t)r * CAPT + idx] : 0u;
      ci[b] = valid ? cidx_g[(size_t)r * CAPT + idx] : (u16)0;
    }
#pragma unroll
    for (int b = 0; b < 8; ++b) {
      if (pv[b] < (unsigned)CAPT) { ckey[pv[b]] = ck[b]; cidx[pv[b]] = ci[b]; }
    }
  }
  __syncthreads();

  bool bad = (sh_bad != 0u) || (cc_u < 64u) || (cc_u > (unsigned)CAPT);

  // bucket histogram (0.01-wide value buckets over [2.0, 4.56))
  if (!bad) {
    for (int s = tid; s < cc; s += 256) {
      float v = u2f(ckey[s]);
      int b = (int)((v - TH_CAND) * 100.0f);
      b = b < 0 ? 0 : (b > 255 ? 255 : b);
      atomicAdd(&hist[b], 1u);
    }
  }
  __syncthreads();
  // suffix scan via shuffle: sscan[b] = # entries in buckets >= b
  {
    int rt = 255 - tid;
    unsigned v = hist[rt];
#pragma unroll
    for (int d = 1; d < 64; d <<= 1) {
      unsigned t = __shfl_up(v, d);
      if (ln >= d) v += t;
    }
    if (ln == 63) wsum[wv] = v;
    __syncthreads();
    unsigned add = 0;
    for (int w = 0; w < wv; ++w) add += wsum[w];
    sscan[rt] = v + add;
    if (tid == 0) sscan[256] = 0u;
    __syncthreads();
    if (sscan[tid] >= 64u && sscan[tid + 1] < 64u) {
      sh_bstar = (unsigned)tid;
      sh_kth = 64u - sscan[tid + 1];
    }
  }
  __syncthreads();

  if (bad || sh_bstar == 0xffffffffu) { if (tid == 0) flags[r] = 1u; return; }
  const int bstar = (int)sh_bstar;
  const unsigned kth = sh_kth;

  // collect bucket-b* values (expected ~2-4)
  for (int s = tid; s < cc; s += 256) {
    float v = u2f(ckey[s]);
    int b = (int)((v - TH_CAND) * 100.0f);
    b = b < 0 ? 0 : (b > 255 ? 255 : b);
    if (b == bstar) {
      unsigned p = atomicAdd(&sh_mcnt, 1u);
      if (p < 64u) bv_l[p] = v;
    }
  }
  __syncthreads();
  if (sh_mcnt > 64u) { if (tid == 0) flags[r] = 1u; return; }
  const int m = (int)sh_mcnt;
  // exact v64 = kth largest within bucket (strict order w/ index tiebreak)
  if (wv == 0 && ln < m) {
    float mine = bv_l[ln];
    int rank = 0;
    for (int j = 0; j < m; ++j) {
      float o = bv_l[j];
      if (o > mine || (o == mine && j < ln)) ++rank;
    }
    if (rank == (int)kth - 1) sh_v64 = mine;
  }
  __syncthreads();
  const float v64 = sh_v64;

  // classify
  const float hi = v64 + 2.f * bandw, lo = v64 - 2.f * bandw;
  for (int s = tid; s < cc; s += 256) {
    float v = u2f(ckey[s]);
    int i = (int)cidx[s];
    if (v > hi) {
      unsigned p = atomicAdd(&sh_ocnt, 1u);
      out_idx[p] = i; out_val[p] = v;
    } else if (v >= lo) {
      unsigned p = atomicAdd(&sh_bcnt, 1u);
      if (p < BANDCAP) { band_idx[p] = i; band_val[p] = v; }
    }
  }
  __syncthreads();
  if (sh_bcnt > BANDCAP) { if (tid == 0) flags[r] = 1u; return; }
  const unsigned nci = sh_ocnt;                       // <= 63
  const unsigned bcnt = sh_bcnt;
  const unsigned remaining = 64u - nci;               // >= 1; bcnt >= remaining

  if (bcnt == remaining) {
    for (unsigned s = tid; s < bcnt; s += 256) {
      out_idx[nci + s] = band_idx[s];
      out_val[nci + s] = band_val[s];
    }
    __syncthreads();
  } else {
    // exact fp64 recompute of band entries (wave-parallel, 8-deep batched)
    const float* xr = x + (size_t)r * 2048;
    for (unsigned bi = wv; bi < bcnt; bi += 4) {
      int c = band_idx[bi];
      const float* wr = WT + (size_t)c * 2048;
      double s = 0.0;
      for (int j0 = 0; j0 < 2048; j0 += 512) {
        float xa[8], wa[8];
#pragma unroll
        for (int u = 0; u < 8; ++u) {
          int j = j0 + ln + 64 * u;
          xa[u] = xr[j];
          wa[u] = wr[j];
        }
#pragma unroll
        for (int u = 0; u < 8; ++u)
          s += (double)xa[u] * (double)wa[u];
      }
#pragma unroll
      for (int off2 = 32; off2 > 0; off2 >>= 1)
        s += __shfl_down(s, off2);
      if (ln == 0) band_ex[bi] = s + (double)benc[c];
    }
    __syncthreads();
    if (tid == 0) {
      for (unsigned i2 = 0; i2 < bcnt; ++i2) picked[i2] = 0;
      for (unsigned s = 0; s < remaining; ++s) {
        int best = -1;
        for (unsigned b2 = 0; b2 < bcnt; ++b2) {
          if (picked[b2]) continue;
          if (best < 0 || band_ex[b2] > band_ex[best] ||
              (band_ex[b2] == band_ex[best] && band_idx[b2] < band_idx[best]))
            best = (int)b2;
        }
        picked[best] = 1;
        out_idx[nci + s] = band_idx[best];
        out_val[nci + s] = (float)band_ex[best];
      }
    }
    __syncthreads();
  }

  if (tid < 64) {
    float v = out_val[tid];
    v = v > 0.f ? v : 0.f;
    out_val[tid] = v;
    topk_idx[(size_t)r * 64 + tid] = out_idx[tid];
    topk_val[(size_t)r * 64 + tid] = v;
  }
  __syncthreads();
  if (tid == 0) {
    float n2 = 0.f;
    for (int s = 0; s < 64; ++s)
      if (out_idx[s] < HDIM) n2 += out_val[s] * out_val[s];
    nh_norm[r] = sqrtf(n2);
    flags[r] = 0u;
  }
}

// ---- repair: full recompute for flagged rows (P ~ 0) -----------------------
__global__ __launch_bounds__(256)
void repair_kernel(const unsigned* __restrict__ flags,
                   const float* __restrict__ x,
                   const float* __restrict__ WT,
                   const float* __restrict__ benc,
                   int* __restrict__ topk_idx,
                   float* __restrict__ topk_val,
                   float* __restrict__ nh_norm)
{
  const int r = blockIdx.x;
  if (flags[r] == 0u) return;
  __shared__ float prerow[16384];   // 64 KB
  __shared__ float xs[2048];
  __shared__ float rv[256];
  __shared__ int   ri[256];
  __shared__ int   oi[64];
  __shared__ float ov[64];
  const int tid = threadIdx.x;
  for (int i = tid; i < 2048; i += 256) xs[i] = x[(size_t)r * 2048 + i];
  __syncthreads();
  for (int c = tid; c < 16384; c += 256) {
    const float* wr = WT + (size_t)c * 2048;
    float s = 0.f;
    for (int j = 0; j < 2048; ++j) s = fmaf(xs[j], wr[j], s);
    prerow[c] = s + benc[c];
  }
  __syncthreads();
  for (int k2 = 0; k2 < 64; ++k2) {
    float bv = -INFINITY; int bi = 16384;
    for (int c = tid; c < 16384; c += 256) {
      float v = prerow[c];
      if (v > bv || (v == bv && c < bi)) { bv = v; bi = c; }
    }
    rv[tid] = bv; ri[tid] = bi;
    __syncthreads();
    for (int s2 = 128; s2 > 0; s2 >>= 1) {
      if (tid < s2) {
        if (rv[tid+s2] > rv[tid] || (rv[tid+s2] == rv[tid] && ri[tid+s2] < ri[tid])) {
          rv[tid] = rv[tid+s2]; ri[tid] = ri[tid+s2];
        }
      }
      __syncthreads();
    }
    if (tid == 0) { oi[k2] = ri[0]; ov[k2] = rv[0]; prerow[ri[0]] = -INFINITY; }
    __syncthreads();
  }
  if (tid < 64) {
    float v = ov[tid]; v = v > 0.f ? v : 0.f;
    topk_idx[(size_t)r * 64 + tid] = oi[tid];
    topk_val[(size_t)r * 64 + tid] = v;
  }
  __syncthreads();
  if (tid == 0) {
    float n2 = 0.f;
    for (int s = 0; s < 64; ++s)
      if (oi[s] < HDIM) { float v = ov[s] > 0.f ? ov[s] : 0.f; n2 += v * v; }
    nh_norm[r] = sqrtf(n2);
  }
}

// -- fused: wdec fp32->fp8 (bid<16384) + ZpTb scatter for even rows (else) ---
__global__ __launch_bounds__(256)
void wdec_scatter_kernel(const float* __restrict__ W,
                         u8* __restrict__ W8, float* __restrict__ scl,
                         const int* __restrict__ topk_idx,
                         const float* __restrict__ topk_val,
                         const float* __restrict__ nh_norm,
                         u16* __restrict__ ZpTb)
{
  const int bid = blockIdx.x;
  const int tid = threadIdx.x;
  if (bid < 16384) {
    __shared__ float red[256];
    const int c = bid;
    const int e0 = tid * 8;
    const float* wr = W + (size_t)c * 2048;
    float4 a = *(const float4*)(wr + e0);
    float4 b = *(const float4*)(wr + e0 + 4);
    float w[8] = {a.x,a.y,a.z,a.w,b.x,b.y,b.z,b.w};
    float mx = 0.f;
#pragma unroll
    for (int i = 0; i < 8; ++i) mx = fmaxf(mx, fabsf(w[i]));
    red[tid] = mx; __syncthreads();
    for (int s = 128; s > 0; s >>= 1) { if (tid < s) red[tid] = fmaxf(red[tid], red[tid+s]); __syncthreads(); }
    const float mxa = red[0];
    const float senc = mxa > 0.f ? 448.f / mxa : 0.f;
    float q[8];
#pragma unroll
    for (int i = 0; i < 8; ++i) q[i] = fminf(fmaxf(w[i] * senc, -448.f), 448.f);
    int p0 = __builtin_amdgcn_cvt_pk_fp8_f32(q[0], q[1], 0, false);
    p0 = __builtin_amdgcn_cvt_pk_fp8_f32(q[2], q[3], p0, true);
    int p1 = __builtin_amdgcn_cvt_pk_fp8_f32(q[4], q[5], 0, false);
    p1 = __builtin_amdgcn_cvt_pk_fp8_f32(q[6], q[7], p1, true);
    uint2 o; o.x = (unsigned)p0; o.y = (unsigned)p1;
    *(uint2*)(W8 + (size_t)c * 2048 + e0) = o;
    if (tid == 0) scl[c] = mxa > 0.f ? mxa / 448.f : 0.f;
  } else {
    // even-row ZpTb scatter: t indexes 2048 even rows x 64 slots
    int t = (bid - 16384) * 256 + tid;
    if (t < 2048 * 64) {
      int b = t >> 6;                 // 0..2047
      int r = 2 * b;                  // even row
      int c = topk_idx[(size_t)r * 64 + (t & 63)];
      float v = topk_val[(size_t)r * 64 + (t & 63)];
      if (c < HDIM) {
        float nrm = nh_norm[r]; nrm = nrm > EPSN ? nrm : EPSN;
        ZpTb[(size_t)c * 2048 + b] = f2bf_rne(v / nrm);
      }
    }
  }
}

// -- fused token kernel: decode + SE (all rows); odd rows additionally write
//    dense z_cur row, x_hat, sim row, lse_row, diag.
__global__ __launch_bounds__(256)
void token_kernel(const int* __restrict__ topk_idx,
                  const float* __restrict__ topk_val,
                  const u8* __restrict__ W8,      // fp8 [16384][2048]
                  const float* __restrict__ scl,  // [16384]
                  const float* __restrict__ bdec,
                  const float* __restrict__ x,
                  const float* __restrict__ nh_norm,
                  const u16* __restrict__ ZpTb,   // bf16 [8192][2048]
                  float* __restrict__ se_full,
                  float* __restrict__ se_high,
                  float* __restrict__ xhat_out,
                  float* __restrict__ zcur_out,
                  float* __restrict__ simb,
                  float* __restrict__ lse_row,
                  float* __restrict__ diag)
{
  __shared__ int sidx[64];
  __shared__ float sval[64];
  __shared__ float rawv[64];
  __shared__ float red[256];
  __shared__ int cidx2[64];
  __shared__ float cval2[64];
  __shared__ u8 zmap[16384];
  __shared__ int scnt;
  const int tid = threadIdx.x;
  const int r = blockIdx.x;
  const int e0 = tid * 8;
  const bool odd = (r & 1);
  if (tid == 0) scnt = 0;
  if (odd) {
    unsigned* zm = (unsigned*)zmap;
#pragma unroll
    for (int j = 0; j < 16; ++j) zm[tid + 256 * j] = 0xFFFFFFFFu;
  }
  if (tid < 64) {
    int c = topk_idx[(size_t)r*64+tid];
    float v = topk_val[(size_t)r*64+tid];
    sidx[tid] = c;
    rawv[tid] = v;
    sval[tid] = v * scl[c];
  }
  __syncthreads();
  if (odd && tid < 64) zmap[sidx[tid]] = (u8)tid;   // distinct indices
  float accf[8], acch[8];
  {
    float4 b0 = *(const float4*)(bdec + e0);
    float4 b1 = *(const float4*)(bdec + e0 + 4);
    accf[0]=b0.x; accf[1]=b0.y; accf[2]=b0.z; accf[3]=b0.w;
    accf[4]=b1.x; accf[5]=b1.y; accf[6]=b1.z; accf[7]=b1.w;
#pragma unroll
    for (int i = 0; i < 8; ++i) acch[i] = accf[i];
  }
  for (int s0 = 0; s0 < 64; s0 += 8) {
    uint2 w[8]; float vf[8], vh[8];
#pragma unroll
    for (int j = 0; j < 8; ++j) {
      int c = sidx[s0 + j];
      float v = sval[s0 + j];
      vf[j] = v;
      vh[j] = (c < HDIM) ? v : 0.f;
      w[j] = *(const uint2*)(W8 + (size_t)c * 2048 + e0);
    }
#pragma unroll
    for (int j = 0; j < 8; ++j) {
      f32x2 f0 = __builtin_amdgcn_cvt_pk_f32_fp8((int)w[j].x, false);
      f32x2 f1 = __builtin_amdgcn_cvt_pk_f32_fp8((int)w[j].x, true);
      f32x2 f2 = __builtin_amdgcn_cvt_pk_f32_fp8((int)w[j].y, false);
      f32x2 f3 = __builtin_amdgcn_cvt_pk_f32_fp8((int)w[j].y, true);
      float wvv[8] = {f0[0],f0[1],f1[0],f1[1],f2[0],f2[1],f3[0],f3[1]};
#pragma unroll
      for (int i = 0; i < 8; ++i) {
        accf[i] = fmaf(vf[j], wvv[i], accf[i]);
        acch[i] = fmaf(vh[j], wvv[i], acch[i]);
      }
    }
  }
  const float* xr = x + (size_t)r * 2048;
  float4 x0 = *(const float4*)(xr + e0);
  float4 x1 = *(const float4*)(xr + e0 + 4);
  float xv[8] = {x0.x,x0.y,x0.z,x0.w,x1.x,x1.y,x1.z,x1.w};
  float sf = 0.f, shs = 0.f;
#pragma unroll
  for (int i = 0; i < 8; ++i) {
    float df = accf[i] - xv[i]; sf += df*df;
    float dh = acch[i] - xv[i]; shs += dh*dh;
  }
  red[tid] = sf; __syncthreads();
  for (int s2=128; s2>0; s2>>=1){ if (tid<s2) red[tid]+=red[tid+s2]; __syncthreads(); }
  if (tid==0) se_full[r] = red[0];
  __syncthreads();
  red[tid] = shs; __syncthreads();
  for (int s2=128; s2>0; s2>>=1){ if (tid<s2) red[tid]+=red[tid+s2]; __syncthreads(); }
  if (tid==0) se_high[r] = red[0];
  if (!odd) return;

  // ---- odd row: dense z_cur row write + x_hat, then sim row + lse_row ----
  {
    float* orow = xhat_out + (size_t)(r >> 1) * 2048;
    float4 o0 = {accf[0],accf[1],accf[2],accf[3]};
    float4 o1 = {accf[4],accf[5],accf[6],accf[7]};
    *(float4*)(orow + e0) = o0;
    *(float4*)(orow + e0 + 4) = o1;
  }
  {
    float* zrow = zcur_out + (size_t)(r >> 1) * 16384;
#pragma unroll
    for (int it = 0; it < 16; ++it) {
      int c0 = it * 1024 + tid * 4;
      float4 o;
      u8 s0m = zmap[c0 + 0]; o.x = (s0m < 64) ? rawv[s0m] : 0.f;
      u8 s1m = zmap[c0 + 1]; o.y = (s1m < 64) ? rawv[s1m] : 0.f;
      u8 s2m = zmap[c0 + 2]; o.z = (s2m < 64) ? rawv[s2m] : 0.f;
      u8 s3m = zmap[c0 + 3]; o.w = (s3m < 64) ? rawv[s3m] : 0.f;
      *(float4*)(zrow + c0) = o;
    }
  }
  const int i = r >> 1;
  __syncthreads();
  if (tid < 64) {
    int c = sidx[tid];
    float v = rawv[tid];
    if (c < HDIM) {
      float nrm = nh_norm[r]; nrm = nrm > EPSN ? nrm : EPSN;
      int p = atomicAdd(&scnt, 1);
      cidx2[p] = c; cval2[p] = v / nrm;
    }
  }
  __syncthreads();
  float acc[8];
#pragma unroll
  for (int ii = 0; ii < 8; ++ii) acc[ii] = 0.f;
  const int m = scnt;
  int s = 0;
  for (; s + 8 <= m; s += 8) {
    u16x8 z[8]; float vv[8];
#pragma unroll
    for (int j = 0; j < 8; ++j) {
      vv[j] = cval2[s + j];
      z[j] = *(const u16x8*)(ZpTb + (size_t)cidx2[s + j] * 2048 + e0);
    }
#pragma unroll
    for (int j = 0; j < 8; ++j)
#pragma unroll
      for (int ii = 0; ii < 8; ++ii)
        acc[ii] = fmaf(vv[j], bf2f(z[j][ii]), acc[ii]);
  }
  for (; s < m; ++s) {
    int c = cidx2[s]; float v = cval2[s];
    u16x8 z8 = *(const u16x8*)(ZpTb + (size_t)c * 2048 + e0);
#pragma unroll
    for (int ii = 0; ii < 8; ++ii)
      acc[ii] = fmaf(v, bf2f(z8[ii]), acc[ii]);
  }
  {
    float* srow = simb + (size_t)i * 2048;
    float4 o0 = {acc[0],acc[1],acc[2],acc[3]};
    float4 o1 = {acc[4],acc[5],acc[6],acc[7]};
    *(float4*)(srow + e0) = o0;
    *(float4*)(srow + e0 + 4) = o1;
  }
  // fused lse_row + diag (acc holds sim[i][e0..e0+7])
  float mx = -INFINITY;
#pragma unroll
  for (int ii = 0; ii < 8; ++ii) mx = fmaxf(mx, acc[ii]);
  if ((i >> 3) == tid) diag[i] = acc[i & 7];
  red[tid] = mx; __syncthreads();
  for (int s2=128; s2>0; s2>>=1){ if (tid<s2) red[tid]=fmaxf(red[tid],red[tid+s2]); __syncthreads(); }
  mx = red[0]; __syncthreads();
  float se = 0.f;
#pragma unroll
  for (int ii = 0; ii < 8; ++ii) se += expf(acc[ii] - mx);
  red[tid] = se; __syncthreads();
  for (int s2=128; s2>0; s2>>=1){ if (tid<s2) red[tid]+=red[tid+s2]; __syncthreads(); }
  if (tid == 0) lse_row[i] = mx + logf(red[0]);
}

// ---------------- fp32 tiled GEMM (fallback) -------------------------------
__global__ __launch_bounds__(256)
void gemm_pre_kernel(const float* __restrict__ A,
                     const float* __restrict__ B,
                     const float* __restrict__ bias,
                     float* __restrict__ C)
{
  __shared__ float As[16][129];
  __shared__ float Bs[16][129];
  const int tid = threadIdx.x;
  const int tx = tid & 15, ty = tid >> 4;
  const int m0 = blockIdx.y * 128;
  const int n0 = blockIdx.x * 128;
  float acc[8][8];
#pragma unroll
  for (int i = 0; i < 8; ++i)
#pragma unroll
    for (int j = 0; j < 8; ++j) acc[i][j] = 0.f;
  const int lk = tid & 15, lm = tid >> 4;
  for (int k0 = 0; k0 < 2048; k0 += 16) {
#pragma unroll
    for (int i = 0; i < 8; ++i) {
      int m = lm + 16 * i;
      As[lk][m] = A[(size_t)(m0 + m) * 2048 + k0 + lk];
    }
#pragma unroll
    for (int i = 0; i < 8; ++i) {
      int idx = tid + 256 * i;
      int kk = idx >> 7, nn = idx & 127;
      Bs[kk][nn] = B[(size_t)(k0 + kk) * 16384 + n0 + nn];
    }
    __syncthreads();
#pragma unroll
    for (int kk = 0; kk < 16; ++kk) {
      float a[8], b[8];
#pragma unroll
      for (int i = 0; i < 8; ++i) a[i] = As[kk][ty + 16 * i];
#pragma unroll
      for (int j = 0; j < 8; ++j) b[j] = Bs[kk][tx + 16 * j];
#pragma unroll
      for (int i = 0; i < 8; ++i)
#pragma unroll
        for (int j = 0; j < 8; ++j) acc[i][j] = fmaf(a[i], b[j], acc[i][j]);
    }
    __syncthreads();
  }
#pragma unroll
  for (int i = 0; i < 8; ++i) {
    int m = m0 + ty + 16 * i;
#pragma unroll
    for (int j = 0; j < 8; ++j) {
      int n = n0 + tx + 16 * j;
      C[(size_t)m * 16384 + n] = acc[i][j] + bias[n];
    }
  }
}

// ---------------- fallback select (fp32 screen, strided resolve) ------------
__global__ __launch_bounds__(256)
void select_fb_kernel(const float* __restrict__ pre,
                      const float* __restrict__ x,
                      const float* __restrict__ Wenc,
                      const float* __restrict__ benc,
                      int row_base, float bandw,
                      int*   __restrict__ topk_idx,
                      float* __restrict__ topk_val,
                      float* __restrict__ nh_norm)
{
  __shared__ unsigned hist[256];
  __shared__ int      band_idx[BANDCAP];
  __shared__ double   band_ex[BANDCAP];
  __shared__ double   red_d[256];
  __shared__ int      out_idx[64];
  __shared__ float    out_val[64];
  __shared__ unsigned char picked[BANDCAP];
  __shared__ unsigned sh_prefix, sh_need, sh_ocnt, sh_bcnt;

  const int tid = threadIdx.x;
  const int lrow = blockIdx.x;
  const int row = row_base + lrow;
  const float* prow = pre + (size_t)lrow * 16384;

  if (tid == 0) { sh_prefix = 0u; sh_need = 64u; }
  __syncthreads();
  for (int level = 24; level >= 0; level -= 8) {
    hist[tid] = 0u;
    __syncthreads();
    unsigned prefix = sh_prefix;
    for (int i = tid; i < 16384; i += 256) {
      unsigned u = f2u(prow[i]);
      bool match = (level == 24) || ((u >> ((level + 8) & 31)) == prefix);
      if (match) atomicAdd(&hist[(u >> level) & 255u], 1u);
    }
    __syncthreads();
    if (tid == 0) {
      unsigned need = sh_need, acc = 0; int q = 0;
      for (int b2 = 255; b2 >= 0; --b2) {
        if (acc + hist[b2] >= need) { q = b2; break; }
        acc += hist[b2];
      }
      sh_prefix = (prefix << 8) | (unsigned)q;
      sh_need = need - acc;
    }
    __syncthreads();
  }
  const float v64 = u2f(sh_prefix);

  if (tid == 0) { sh_ocnt = 0u; sh_bcnt = 0u; }
  __syncthreads();
  const float hi = v64 + 2.f * bandw, lo = v64 - 2.f * bandw;
  for (int i = tid; i < 16384; i += 256) {
    float v = prow[i];
    if (v > hi) {
      unsigned p = atomicAdd(&sh_ocnt, 1u);
      out_idx[p] = i; out_val[p] = v;
    } else if (v >= lo) {
      unsigned p = atomicAdd(&sh_bcnt, 1u);
      if (p < BANDCAP) { band_idx[p] = i; }
    }
  }
  __syncthreads();
  const unsigned nci = sh_ocnt;
  const unsigned bcnt = sh_bcnt < BANDCAP ? sh_bcnt : BANDCAP;
  const unsigned remaining = 64u - nci;

  if (bcnt == remaining) {
    for (unsigned s = tid; s < bcnt; s += 256) {
      int c = band_idx[s];
      out_idx[nci + s] = c;
      out_val[nci + s] = prow[c];
    }
    __syncthreads();
  } else {
    const float* xr = x + (size_t)row * 2048;
    for (unsigned bi = 0; bi < bcnt; ++bi) {
      int c = band_idx[bi];
      double part = 0.0;
#pragma unroll
      for (int j2 = 0; j2 < 8; ++j2) {
        int kk = tid + 256 * j2;
        part += (double)xr[kk] * (double)Wenc[(size_t)kk * 16384 + c];
      }
      red_d[tid] = part;
      __syncthreads();
      for (int sft = 128; sft > 0; sft >>= 1) {
        if (tid < sft) red_d[tid] += red_d[tid + sft];
        __syncthreads();
      }
      if (tid == 0) band_ex[bi] = red_d[0] + (double)benc[c];
      __syncthreads();
    }
    if (tid == 0) {
      for (unsigned i2 = 0; i2 < bcnt; ++i2) picked[i2] = 0;
      for (unsigned s = 0; s < remaining; ++s) {
        int best = -1;
        for (unsigned b2 = 0; b2 < bcnt; ++b2) {
          if (picked[b2]) continue;
          if (best < 0 || band_ex[b2] > band_ex[best] ||
              (band_ex[b2] == band_ex[best] && band_idx[b2] < band_idx[best]))
            best = (int)b2;
        }
        picked[best] = 1;
        out_idx[nci + s] = band_idx[best];
        out_val[nci + s] = (float)band_ex[best];
      }
    }
    __syncthreads();
  }

  if (tid < 64) {
    float v = out_val[tid];
    v = v > 0.f ? v : 0.f;
    out_val[tid] = v;
    topk_idx[(size_t)row * 64 + tid] = out_idx[tid];
    topk_val[(size_t)row * 64 + tid] = v;
  }
  __syncthreads();
  if (tid == 0) {
    float n2 = 0.f;
    for (int s = 0; s < 64; ++s)
      if (out_idx[s] < HDIM) n2 += out_val[s] * out_val[s];
    nh_norm[row] = sqrtf(n2);
  }
}

__global__ __launch_bounds__(256)
void scatter_f32_kernel(const int* __restrict__ topk_idx,
                        const float* __restrict__ topk_val,
                        const float* __restrict__ nh_norm,
                        float* __restrict__ zcur_out,
                        float* __restrict__ ZpT)
{
  int t = blockIdx.x * blockDim.x + threadIdx.x;
  if (t >= NROWS * 64) return;
  int r = t >> 6;
  int c = topk_idx[t];
  float v = topk_val[t];
  int b = r >> 1;
  if (r & 1) {
    zcur_out[(size_t)b * 16384 + c] = v;
  } else if (c < HDIM) {
    float nrm = nh_norm[r]; nrm = nrm > EPSN ? nrm : EPSN;
    ZpT[(size_t)c * 2048 + b] = v / nrm;
  }
}

__global__ __launch_bounds__(256)
void decode_f32_kernel(const int* __restrict__ topk_idx,
                       const float* __restrict__ topk_val,
                       const float* __restrict__ Wdec,
                       const float* __restrict__ bdec,
                       const float* __restrict__ x,
                       float* __restrict__ se_full,
                       float* __restrict__ se_high,
                       float* __restrict__ xhat_out)
{
  __shared__ int sidx[64];
  __shared__ float sval[64];
  __shared__ float red[256];
  const int tid = threadIdx.x;
  const int r = blockIdx.x;
  if (tid < 64) { sidx[tid] = topk_idx[(size_t)r*64+tid]; sval[tid] = topk_val[(size_t)r*64+tid]; }
  __syncthreads();
  float accf[8], acch[8];
#pragma unroll
  for (int i = 0; i < 8; ++i) { float b = bdec[tid + 256*i]; accf[i] = b; acch[i] = b; }
  for (int s = 0; s < 64; ++s) {
    int c = sidx[s]; float v = sval[s];
    const float* wr = Wdec + (size_t)c * 2048;
    bool high = (c < HDIM);
#pragma unroll
    for (int i = 0; i < 8; ++i) {
      float w = wr[tid + 256*i];
      accf[i] = fmaf(v, w, accf[i]);
      if (high) acch[i] = fmaf(v, w, acch[i]);
    }
  }
  const float* xr = x + (size_t)r * 2048;
  float sf = 0.f, shs = 0.f;
#pragma unroll
  for (int i = 0; i < 8; ++i) {
    float xv = xr[tid + 256*i];
    float df = accf[i] - xv; sf += df*df;
    float dh = acch[i] - xv; shs += dh*dh;
  }
  red[tid] = sf; __syncthreads();
  for (int s2=128; s2>0; s2>>=1){ if (tid<s2) red[tid]+=red[tid+s2]; __syncthreads(); }
  if (tid==0) se_full[r] = red[0];
  __syncthreads();
  red[tid] = shs; __syncthreads();
  for (int s2=128; s2>0; s2>>=1){ if (tid<s2) red[tid]+=red[tid+s2]; __syncthreads(); }
  if (tid==0) se_high[r] = red[0];
  if (r & 1) {
    float* orow = xhat_out + (size_t)(r >> 1) * 2048;
#pragma unroll
    for (int i = 0; i < 8; ++i) orow[tid + 256*i] = accf[i];
  }
}

__global__ __launch_bounds__(256)
void sim_f32_kernel(const int* __restrict__ topk_idx,
                    const float* __restrict__ topk_val,
                    const float* __restrict__ nh_norm,
                    const float* __restrict__ ZpT,
                    float* __restrict__ sim)
{
  __shared__ int cidx2[64];
  __shared__ float cval2[64];
  __shared__ int scnt;
  const int tid = threadIdx.x;
  const int i = blockIdx.x;
  const int r = 2 * i + 1;
  if (tid == 0) scnt = 0;
  __syncthreads();
  if (tid < 64) {
    int c = topk_idx[(size_t)r*64+tid];
    float v = topk_val[(size_t)r*64+tid];
    if (c < HDIM) {
      float nrm = nh_norm[r]; nrm = nrm > EPSN ? nrm : EPSN;
      int p = atomicAdd(&scnt, 1);
      cidx2[p] = c; cval2[p] = v / nrm;
    }
  }
  __syncthreads();
  float acc[8];
#pragma unroll
  for (int ii = 0; ii < 8; ++ii) acc[ii] = 0.f;
  int m = scnt;
  for (int s = 0; s < m; ++s) {
    int c = cidx2[s]; float v = cval2[s];
    const float* zr = ZpT + (size_t)c * 2048;
#pragma unroll
    for (int ii = 0; ii < 8; ++ii)
      acc[ii] = fmaf(v, zr[tid + 256*ii], acc[ii]);
  }
  float* srow = sim + (size_t)i * 2048;
#pragma unroll
  for (int ii = 0; ii < 8; ++ii) srow[tid + 256*ii] = acc[ii];
}

// lse_row (fallback path only; main path fuses it into token_kernel)
__global__ __launch_bounds__(256)
void lse_row_kernel(const float* __restrict__ sim,
                    float* __restrict__ lse_row, float* __restrict__ diag)
{
  __shared__ float red[256];
  const int tid = threadIdx.x; const int i = blockIdx.x;
  const int e0 = tid * 8;
  const float* srow = sim + (size_t)i * 2048;
  float4 v0 = *(const float4*)(srow + e0);
  float4 v1 = *(const float4*)(srow + e0 + 4);
  float vals[8] = {v0.x,v0.y,v0.z,v0.w,v1.x,v1.y,v1.z,v1.w};
  float mx = -INFINITY;
#pragma unroll
  for (int ii=0; ii<8; ++ii) mx = fmaxf(mx, vals[ii]);
  if ((i >> 3) == tid) diag[i] = vals[i & 7];
  red[tid]=mx; __syncthreads();
  for (int s=128;s>0;s>>=1){ if (tid<s) red[tid]=fmaxf(red[tid],red[tid+s]); __syncthreads(); }
  mx = red[0]; __syncthreads();
  float se=0.f;
#pragma unroll
  for (int ii=0;ii<8;++ii) se += expf(vals[ii]-mx);
  red[tid]=se; __syncthreads();
  for (int s=128;s>0;s>>=1){ if (tid<s) red[tid]+=red[tid+s]; __syncthreads(); }
  if (tid==0) lse_row[i] = mx + logf(red[0]);
}

// coalesced online-softmax over columns: 256 blocks x 8 cols, 32 row-thr/col
__global__ __launch_bounds__(256)
void lse_col_kernel(const float* __restrict__ sim, float* __restrict__ lse_col)
{
  __shared__ float ml[32][9], sl[32][9];
  const int tid = threadIdx.x;
  const int c = tid & 7, rr = tid >> 3;
  const int col = blockIdx.x * 8 + c;
  float m = -INFINITY, s = 0.f;
  for (int r = rr; r < 2048; r += 32) {
    float v = sim[(size_t)r * 2048 + col];
    float mn = fmaxf(m, v);
    s = s * expf(m - mn) + expf(v - mn);
    m = mn;
  }
  ml[rr][c] = m; sl[rr][c] = s;
  __syncthreads();
  if (rr == 0) {
    float M = ml[0][c];
#pragma unroll
    for (int i = 1; i < 32; ++i) M = fmaxf(M, ml[i][c]);
    float S = 0.f;
#pragma unroll
    for (int i = 0; i < 32; ++i) S += sl[i][c] * expf(ml[i][c] - M);
    lse_col[col] = M + logf(S);
  }
}

// ---------------- final scalar ----------------------------------------------
__global__ __launch_bounds__(256)
void final_kernel(const float* __restrict__ se_full, const float* __restrict__ se_high,
                  const float* __restrict__ lse_row, const float* __restrict__ lse_col,
                  const float* __restrict__ diag, float* __restrict__ out0)
{
  __shared__ float red[256];
  const int tid = threadIdx.x;
  float s1 = 0.f;
  for (int i = tid; i < 4096; i += 256) s1 += se_full[i] + se_high[i];
  red[tid]=s1; __syncthreads();
  for (int s=128;s>0;s>>=1){ if (tid<s) red[tid]+=red[tid+s]; __syncthreads(); }
  float matr = red[0]; __syncthreads();
  float s2 = 0.f;
  for (int i = tid; i < 2048; i += 256) s2 += (lse_row[i]-diag[i]) + (lse_col[i]-diag[i]);
  red[tid]=s2; __syncthreads();
  for (int s=128;s>0;s>>=1){ if (tid<s) red[tid]+=red[tid+s]; __syncthreads(); }
  if (tid == 0) {
    float l_matr  = matr / (2048.f * 2048.f);
    float l_contr = 0.5f * (red[0] / 2048.f);
    out0[0] = l_matr + l_contr;
  }
}

extern "C" void kernel_launch(void* const* d_in, const int* in_sizes, int n_in,
                              void* d_out, int out_size, void* d_ws, size_t ws_size,
                              hipStream_t stream)
{
  const float* x    = (const float*)d_in[0];
  const float* Wenc = (const float*)d_in[1];
  const float* Wdec = (const float*)d_in[2];
  const float* benc = (const float*)d_in[3];
  const float* bdec = (const float*)d_in[4];
  float* out = (float*)d_out;
  float* xhat_out = out + 1;
  float* zcur_out = out + 1 + (size_t)2048 * 2048;
  (void)in_sizes; (void)n_in; (void)out_size;

  char* ws = (char*)d_ws;
  size_t off = 0;
  auto alloc = [&](size_t bytes) {
    char* p = ws + off; off += (bytes + 255) & ~(size_t)255; return p;
  };
  int*      tki     = (int*)     alloc((size_t)NROWS * 64 * 4);
  float*    tkv     = (float*)   alloc((size_t)NROWS * 64 * 4);
  float*    nh_norm = (float*)   alloc((size_t)NROWS * 4);
  float*    se_f    = (float*)   alloc((size_t)NROWS * 4);
  float*    se_h    = (float*)   alloc((size_t)NROWS * 4);
  float*    lse_r   = (float*)   alloc((size_t)2048 * 4);
  float*    lse_c   = (float*)   alloc((size_t)2048 * 4);
  float*    diag    = (float*)   alloc((size_t)2048 * 4);
  f16*      Axh     = (f16*)     alloc((size_t)NROWS * D_IN * 2);      // 16 MiB
  unsigned* ckey_g  = (unsigned*)alloc((size_t)NROWS * CAPT * 4);      // 32 MiB
  u16*      cidx_g  = (u16*)     alloc((size_t)NROWS * CAPT * 2);      // 16 MiB
  unsigned* ccnt    = (unsigned*)alloc((size_t)NROWS * NTILE * 4);     //  2 MiB
  unsigned* flags   = (unsigned*)alloc((size_t)NROWS * 4);
  char*     R1      = alloc((size_t)D_SAE * D_IN * 2);                 // 64 MiB: Th -> {W8, scl}
  char*     R2      = alloc((size_t)D_SAE * D_IN * 4);                 // 128 MiB: WT -> ZpTb+sim
  size_t need = off;

  f16*   Th    = (f16*)R1;
  u8*    W8    = (u8*)R1;                                       // 32 MiB
  float* scl   = (float*)(R1 + (size_t)D_SAE * D_IN);           // 64 KiB
  float* WT    = (float*)R2;
  u16*   ZpTb  = (u16*)R2;                                      // 32 MiB
  float* simb  = (float*)(R2 + (size_t)8192 * 2048 * 2);        // 16 MiB

  if (ws_size >= need) {
    // ---- fp16 MFMA screen -> segmented candidate lists -> certified select --
    pre_kernel<<<16384, 256, 0, stream>>>(x, Wenc, Axh, Th, WT);
    gemm_f16_kernel<<<1024, 512, 0, stream>>>(Axh, Th, benc, ckey_g, cidx_g, ccnt);
    select_compact_kernel<<<NROWS, 256, 0, stream>>>(ckey_g, cidx_g, ccnt, x, WT, benc,
        BANDW_F16, tki, tkv, nh_norm, flags);
    repair_kernel<<<NROWS, 256, 0, stream>>>(flags, x, WT, benc, tki, tkv, nh_norm);
    // Th dead after gemm; WT dead after repair (stream-ordered)
    hipMemsetAsync(ZpTb, 0, (size_t)8192 * 2048 * 2, stream);
    wdec_scatter_kernel<<<16384 + 512, 256, 0, stream>>>(Wdec, W8, scl,
        tki, tkv, nh_norm, ZpTb);
    token_kernel<<<NROWS, 256, 0, stream>>>(tki, tkv, W8, scl, bdec, x, nh_norm, ZpTb,
        se_f, se_h, xhat_out, zcur_out, simb, lse_r, diag);
    lse_col_kernel<<<256, 256, 0, stream>>>(simb, lse_c);
    final_kernel<<<1, 256, 0, stream>>>(se_f, se_h, lse_r, lse_c, diag, out);
  } else {
    // ---- fp32 fallback (smaller footprint) ----
    off = 0;
    float* pre2  = (float*)alloc((size_t)CHUNK * 16384 * 4);
    int*   tki2  = (int*)  alloc((size_t)NROWS * 64 * 4);
    float* tkv2  = (float*)alloc((size_t)NROWS * 64 * 4);
    float* nh2   = (float*)alloc((size_t)NROWS * 4);
    float* sef2  = (float*)alloc((size_t)NROWS * 4);
    float* seh2  = (float*)alloc((size_t)NROWS * 4);
    float* lr2   = (float*)alloc((size_t)2048 * 4);
    float* lc2   = (float*)alloc((size_t)2048 * 4);
    float* dg2   = (float*)alloc((size_t)2048 * 4);
    float* ZpT2  = (float*)alloc((size_t)8192 * 2048 * 4);
    float* sim2  = (float*)alloc((size_t)2048 * 2048 * 4);
    hipMemsetAsync(zcur_out, 0, (size_t)2048 * 16384 * 4, stream);
    for (int ch = 0; ch < 4; ++ch) {
      dim3 g(128, 8);
      gemm_pre_kernel<<<g, 256, 0, stream>>>(x + (size_t)ch * CHUNK * 2048, Wenc, benc, pre2);
      select_fb_kernel<<<CHUNK, 256, 0, stream>>>(pre2, x, Wenc, benc,
          ch * CHUNK, BANDW_F32, tki2, tkv2, nh2);
    }
    hipMemsetAsync(ZpT2, 0, (size_t)8192 * 2048 * 4, stream);
    scatter_f32_kernel<<<(NROWS * 64) / 256, 256, 0, stream>>>(tki2, tkv2, nh2, zcur_out, ZpT2);
    decode_f32_kernel<<<NROWS, 256, 0, stream>>>(tki2, tkv2, Wdec, bdec, x, sef2, seh2, xhat_out);
    sim_f32_kernel<<<2048, 256, 0, stream>>>(tki2, tkv2, nh2, ZpT2, sim2);
    lse_row_kernel<<<2048, 256, 0, stream>>>(sim2, lr2, dg2);
    lse_col_kernel<<<256, 256, 0, stream>>>(sim2, lc2);
    final_kernel<<<1, 256, 0, stream>>>(sef2, seh2, lr2, lc2, dg2, out);
  }
}